// Round 15
// baseline (315.209 us; speedup 1.0000x reference)
//
#include <hip/hip_runtime.h>
#include <math.h>

#define B_   8
#define C_   256
#define N_   4096
#define CQK_ 64
#define JS_  8
#define NSPLIT 4
#define NRANGE (N_ / NSPLIT)   // 1024

// Qf is pre-scaled by sqrt(log2(e)) so q.k logits are in log2 domain: exp -> v_exp_f32.
#define SCQ 1.20110674f
#define THR2 11.54f            // defer-max threshold (8 nats in log2 units)

typedef __attribute__((ext_vector_type(8))) short short8v;    // 8 x bf16 (4 VGPRs)
typedef __attribute__((ext_vector_type(4))) short short4v;    // 4 x bf16 (8B)
typedef __attribute__((ext_vector_type(4))) float f32x4;
typedef __attribute__((ext_vector_type(16))) float f32x16;
typedef __attribute__((ext_vector_type(4))) unsigned int uint4v;

__device__ __forceinline__ unsigned short f2bf(float f) {
    unsigned u = __float_as_uint(f);
    u += 0x7fffu + ((u >> 16) & 1u);
    return (unsigned short)(u >> 16);
}
__device__ __forceinline__ float bf2f(unsigned short h) {
    return __uint_as_float((unsigned)h << 16);
}
// Single-instruction exp2 via COMPILER BUILTIN (hazard-safe; r10's raw asm broke TRANS->VALU
// wait-state insertion). r14 A/B: halves pv VALU cycles (34->19% busy).
__device__ __forceinline__ float fexp2(float x) { return __builtin_amdgcn_exp2f(x); }
// NOTE: do NOT barrier-phase-lock independent waves (r11: 148->355us, zero L1 reuse gained).
// NOTE: m=64/wave spills (r12: 256-VGPR cap, 1 wave/SIMD, 148->349us).
// NOTE: do NOT pointer-bump/unroll-2 the pv loop (r13: 148->351us, load schedule destroyed).
// r14: pv is grid-occupancy-limited (2 waves/SIMD); NSPLIT=4 doubles waves at equal L2 traffic.

// Fragment-major layouts (one wave load = contiguous 1KB):
//  Qf[b][nt(32n)][ks(16c)][lane][8]: element (n = nt*32 + (lane&31), c = ks*16 + (lane>>5)*8 + j)
//  Vf[b][nt16(16n)][cb(32c)][lane][8]: element (c = cb*32 + (lane&31), n = nt16*16 + (lane>>5)*8 + j)

// ------------------------------------------------ weights fp32 -> bf16 (row-major, packed)
__global__ __launch_bounds__(256) void wcvt_kernel(const float* __restrict__ wqk,
                                                   const float* __restrict__ wv,
                                                   const float* __restrict__ wt,
                                                   unsigned short* __restrict__ wh) {
    int i = (blockIdx.x * 256 + threadIdx.x) * 4;   // 144*256*4 = 147456 total
    const float* src; int off;
    if (i < 16384)      { src = wqk; off = i; }
    else if (i < 81920) { src = wv;  off = i - 16384; }
    else                { src = wt;  off = i - 81920; }
    float4 v = *(const float4*)(src + off);
    short4v o;
    o[0] = (short)f2bf(v.x); o[1] = (short)f2bf(v.y);
    o[2] = (short)f2bf(v.z); o[3] = (short)f2bf(v.w);
    *(short4v*)(wh + i) = o;
}

// --------------------------- xs = x + xyz (fp32 [b][c][n]) AND xst bf16 transposed [b][n][c]
__global__ __launch_bounds__(256) void addt_kernel(const float* __restrict__ x,
                                                   const float* __restrict__ xyz,
                                                   float* __restrict__ xs,
                                                   unsigned short* __restrict__ xst) {
    __shared__ float st[64][65];
    const int tid = threadIdx.x;
    const int n0 = blockIdx.x * 64, c0 = blockIdx.y * 64, b = blockIdx.z;
    const size_t base = ((size_t)b * C_ + c0) * N_ + n0;
#pragma unroll
    for (int r = 0; r < 4; ++r) {
        int c = r * 16 + (tid >> 4);
        int nc = (tid & 15) * 4;
        size_t off = base + (size_t)c * N_ + nc;
        float4 xv = *(const float4*)(x + off);
        float4 yv = *(const float4*)(xyz + off);
        float4 s = make_float4(xv.x + yv.x, xv.y + yv.y, xv.z + yv.z, xv.w + yv.w);
        *(float4*)(xs + off) = s;
        st[c][nc] = s.x; st[c][nc + 1] = s.y; st[c][nc + 2] = s.z; st[c][nc + 3] = s.w;
    }
    __syncthreads();
    int n = tid >> 2, cc = (tid & 3) * 16;
    short8v p0, p1;
#pragma unroll
    for (int j = 0; j < 8; ++j) {
        p0[j] = (short)f2bf(st[cc + j][n]);
        p1[j] = (short)f2bf(st[cc + 8 + j][n]);
    }
    size_t ob = ((size_t)b * N_ + n0 + n) * 256 + c0 + cc;
    *(short8v*)(xst + ob) = p0;
    *(short8v*)(xst + ob + 8) = p1;
}

// --------------------- Q-conv (MFMA): out Qf fragment-major, pre-scaled by SCQ (log2 domain)
__global__ __launch_bounds__(256, 4) void convq_kernel(const unsigned short* __restrict__ xst,
                                                       const unsigned short* __restrict__ wh,
                                                       const float* __restrict__ bias,
                                                       unsigned short* __restrict__ Qf) {
    const int tid = threadIdx.x, wave = tid >> 6, lane = tid & 63, q = lane & 15, g = lane >> 4;
    const int n0 = blockIdx.x * 64, b = blockIdx.y;
    const unsigned short* xb = xst + (size_t)b * N_ * 256;
    f32x4 acc[4];
#pragma unroll
    for (int j = 0; j < 4; ++j) acc[j] = (f32x4){0.f, 0.f, 0.f, 0.f};
    for (int ks = 0; ks < 8; ++ks) {
        short8v aw = *(const short8v*)(wh + (size_t)(wave * 16 + q) * 256 + ks * 32 + 8 * g);
#pragma unroll
        for (int j = 0; j < 4; ++j) {
            short8v bx = *(const short8v*)(xb + (size_t)(n0 + j * 16 + q) * 256 + ks * 32 + 8 * g);
            acc[j] = __builtin_amdgcn_mfma_f32_16x16x32_bf16(aw, bx, acc[j], 0, 0, 0);
        }
    }
    // element (n = n0+j*16+q, c = wave*16+4g+r) -> Qf[(b*128+nt)*4+ks=wave][hi=g>>1][l31][jj=4(g&1)+r]
#pragma unroll
    for (int j = 0; j < 4; ++j) {
        short4v pk;
#pragma unroll
        for (int r = 0; r < 4; ++r)
            pk[r] = (short)f2bf((acc[j][r] + bias[wave * 16 + 4 * g + r]) * SCQ);
        const int n = n0 + j * 16 + q;
        size_t a = ((((size_t)b * 128 + (n >> 5)) * 4 + wave) * 64 + (g >> 1) * 32 + (n & 31)) * 8
                   + (g & 1) * 4;
        *(short4v*)(Qf + a) = pk;
    }
}

// --------------------- V-conv (MFMA): out Vf fragment-major, PRE-SCALED by rsinv[n]
__global__ __launch_bounds__(512, 2) void convv_kernel(const unsigned short* __restrict__ xst,
                                                       const unsigned short* __restrict__ wh,
                                                       const float* __restrict__ bias,
                                                       const float* __restrict__ rsinv,
                                                       unsigned short* __restrict__ Vf) {
    const int tid = threadIdx.x, wave = tid >> 6, lane = tid & 63, q = lane & 15, g = lane >> 4;
    const int n0 = blockIdx.x * 64, o0 = blockIdx.y * 128, b = blockIdx.z;
    const int oo = o0 + wave * 16;
    const unsigned short* xb = xst + (size_t)b * N_ * 256;
    const float* rsb = rsinv + (size_t)b * N_;
    f32x4 acc[4];
#pragma unroll
    for (int j = 0; j < 4; ++j) acc[j] = (f32x4){0.f, 0.f, 0.f, 0.f};
    for (int ks = 0; ks < 8; ++ks) {
        short8v bw = *(const short8v*)(wh + (size_t)(oo + q) * 256 + ks * 32 + 8 * g);
#pragma unroll
        for (int j = 0; j < 4; ++j) {
            short8v ax = *(const short8v*)(xb + (size_t)(n0 + j * 16 + q) * 256 + ks * 32 + 8 * g);
            acc[j] = __builtin_amdgcn_mfma_f32_16x16x32_bf16(ax, bw, acc[j], 0, 0, 0);
        }
    }
    float bo = bias[oo + q];
    const int c = oo + q;
    // element (c, n = n0+j*16+4g+r) -> Vf[(b*256 + n0/16 + j)*8 + c>>5][hi=g>>1][c&31][4(g&1)+r]
#pragma unroll
    for (int j = 0; j < 4; ++j) {
        f32x4 rs4 = *(const f32x4*)(rsb + n0 + j * 16 + 4 * g);
        short4v pk;
#pragma unroll
        for (int r = 0; r < 4; ++r) pk[r] = (short)f2bf((acc[j][r] + bo) * rs4[r]);
        size_t a = ((((size_t)b * 256 + (n0 >> 4) + j) * 8 + (c >> 5)) * 64
                    + (g >> 1) * 32 + (c & 31)) * 8 + (g & 1) * 4;
        *(short4v*)(Vf + a) = pk;
    }
}

// ------------------ pass A: row softmax stats via 32x32 MFMA on Qf, log2 domain, defer-max
__global__ __launch_bounds__(256) void rowstats_mfma(const unsigned short* __restrict__ Qf,
                                                     float* __restrict__ pmax,
                                                     float* __restrict__ psum) {
    const int tid = threadIdx.x;
    const int wave = tid >> 6, lane = tid & 63, l31 = lane & 31;
    const int bid = blockIdx.x;
    const int b  = bid & 7;
    const int it = (bid >> 3) & 31;
    const int js = bid >> 8;
    const int i0 = it * 128 + wave * 32;
    const unsigned short* Qb = Qf + (size_t)b * 128 * 4 * 512;

    short8v bqi[4];   // B-frags: cols i (this wave's stat rows)
#pragma unroll
    for (int ks = 0; ks < 4; ++ks)
        bqi[ks] = *(const short8v*)(Qb + (((size_t)(i0 >> 5) * 4 + ks) * 64 + lane) * 8);

    float m = -1e30f, s = 0.f;
    const int jbeg = js * (N_ / JS_);
    for (int j0 = jbeg; j0 < jbeg + N_ / JS_; j0 += 32) {
        short8v an[4];
#pragma unroll
        for (int ks = 0; ks < 4; ++ks)
            an[ks] = *(const short8v*)(Qb + (((size_t)(j0 >> 5) * 4 + ks) * 64 + lane) * 8);
        f32x16 e;
#pragma unroll
        for (int r = 0; r < 16; ++r) e[r] = 0.f;
#pragma unroll
        for (int ks = 0; ks < 4; ++ks)
            e = __builtin_amdgcn_mfma_f32_32x32x16_bf16(an[ks], bqi[ks], e, 0, 0, 0);
        float pm = e[0];
#pragma unroll
        for (int r = 1; r < 16; ++r) pm = fmaxf(pm, e[r]);
        if (!__all(pm <= m + THR2)) {   // defer-max: rescale only on violation (rare)
            float mn = fmaxf(m, pm);
            s *= fexp2(m - mn);
            m = mn;
        }
#pragma unroll
        for (int r = 0; r < 16; ++r) s += fexp2(e[r] - m);
    }
    // merge hi/lo halves (each holds complementary j-subsets of column i = l31)
    {
        float mo = __shfl_xor(m, 32);
        float so = __shfl_xor(s, 32);
        float mn = fmaxf(m, mo);
        s = s * fexp2(m - mn) + so * fexp2(mo - mn);
        m = mn;
    }
    if (lane < 32) {
        size_t o = ((size_t)js * B_ + b) * N_ + i0 + l31;
        pmax[o] = m;
        psum[o] = s;
    }
}

// rowmerge: stores NEGATED rm (pv uses it directly as the MFMA C-init) + rsinv
__global__ __launch_bounds__(256) void rowmerge_kernel(const float* __restrict__ pmax,
                                                       const float* __restrict__ psum,
                                                       float* __restrict__ rmneg,
                                                       float* __restrict__ rsinv) {
    size_t i = (size_t)blockIdx.x * 256 + threadIdx.x;
    float m = -1e30f;
#pragma unroll
    for (int js = 0; js < JS_; ++js) m = fmaxf(m, pmax[(size_t)js * B_ * N_ + i]);
    float s = 0.f;
#pragma unroll
    for (int js = 0; js < JS_; ++js)
        s += psum[(size_t)js * B_ * N_ + i] * fexp2(pmax[(size_t)js * B_ * N_ + i] - m);
    rmneg[i] = -m;
    rsinv[i] = 1.f / s;
}

// --------- pass B (r9 schedule verbatim, NSPLIT=4): barrier-free, LDS-free, fragment-major.
// energy 32x32x16 (C-init = -rm) -> exp2 -> cvt_pk -> permlane32_swap -> PV 32x32x16.
// Splits 0,1 write partials to pxr_lo (ws); splits 2,3 to pxr_hi (d_out, dead until convt).
__global__ __launch_bounds__(256, 2) void pv_mfma32(const unsigned short* __restrict__ Qf,
                                                    const unsigned short* __restrict__ Vf,
                                                    const float* __restrict__ rmneg,
                                                    const float* __restrict__ rsinv,
                                                    unsigned short* __restrict__ pxr_lo,
                                                    unsigned short* __restrict__ pxr_hi,
                                                    float* __restrict__ pcs) {
    const int tid = threadIdx.x;
    const int wave = tid >> 6, lane = tid & 63, l31 = lane & 31, hi = lane >> 5;
    const int bid = blockIdx.x;
    const int b  = bid & 7;                 // XCD-pinned: one batch per XCD
    const int mc = (bid >> 3) & 31;
    const int ns = bid >> 8;                // 0..3
    const int m0 = mc * 128 + wave * 32;    // this wave's m-tile
    const int nbeg = ns * NRANGE;
    const unsigned short* Qb = Qf + (size_t)b * 128 * 4 * 512;
    const unsigned short* Vb = Vf + (size_t)b * 256 * 8 * 512;
    const float* rmb = rmneg + (size_t)b * N_;
    const float* rsb = rsinv + (size_t)b * N_;

    // persistent energy B-frags: cols m = m0+l31
    short8v bqm[4];
#pragma unroll
    for (int ks = 0; ks < 4; ++ks)
        bqm[ks] = *(const short8v*)(Qb + (((size_t)(m0 >> 5) * 4 + ks) * 64 + lane) * 8);

    f32x16 acc[8];
#pragma unroll
    for (int cb = 0; cb < 8; ++cb)
#pragma unroll
        for (int r = 0; r < 16; ++r) acc[cb][r] = 0.f;
    f32x4 csum4 = {0.f, 0.f, 0.f, 0.f};

#pragma unroll 1
    for (int it = 0; it < NRANGE / 32; ++it) {
        const int n0 = nbeg + it * 32;
        const int nt = n0 >> 5;
        // A-frags (rows n) — contiguous 1KB each
        short8v an[4];
#pragma unroll
        for (int ks = 0; ks < 4; ++ks)
            an[ks] = *(const short8v*)(Qb + (((size_t)nt * 4 + ks) * 64 + lane) * 8);
        // stats (broadcast loads, L2-hot): reg r+4s -> n = n0 + 8s + 4hi + r
        f32x4 rmn[4], rs[4];
#pragma unroll
        for (int s = 0; s < 4; ++s) {
            rmn[s] = *(const f32x4*)(rmb + n0 + 8 * s + 4 * hi);
            rs[s]  = *(const f32x4*)(rsb + n0 + 8 * s + 4 * hi);
        }
        // energy: C-init = -rm (free subtraction), 4 chained k-steps
        f32x16 e;
#pragma unroll
        for (int s = 0; s < 4; ++s) {
            e[4 * s + 0] = rmn[s][0]; e[4 * s + 1] = rmn[s][1];
            e[4 * s + 2] = rmn[s][2]; e[4 * s + 3] = rmn[s][3];
        }
#pragma unroll
        for (int ks = 0; ks < 4; ++ks)
            e = __builtin_amdgcn_mfma_f32_32x32x16_bf16(an[ks], bqm[ks], e, 0, 0, 0);
        // exp2 (single v_exp_f32 each) + csum + pack to bf16 dword pairs
        unsigned dw[8];
#pragma unroll
        for (int s = 0; s < 4; ++s) {
            float p0 = fexp2(e[4 * s + 0]);
            float p1 = fexp2(e[4 * s + 1]);
            float p2 = fexp2(e[4 * s + 2]);
            float p3 = fexp2(e[4 * s + 3]);
            csum4[s] += (p0 * rs[s][0] + p1 * rs[s][1]) + (p2 * rs[s][2] + p3 * rs[s][3]);
            asm("v_cvt_pk_bf16_f32 %0, %1, %2" : "=v"(dw[2 * s + 0]) : "v"(p0), "v"(p1));
            asm("v_cvt_pk_bf16_f32 %0, %1, %2" : "=v"(dw[2 * s + 1]) : "v"(p2), "v"(p3));
        }
        // lane-half exchange: a' = [a_lo|b_lo], b' = [a_hi|b_hi]  (exact B-frag words)
        asm("v_permlane32_swap_b32 %0, %1" : "+v"(dw[0]), "+v"(dw[2]));
        asm("v_permlane32_swap_b32 %0, %1" : "+v"(dw[1]), "+v"(dw[3]));
        asm("v_permlane32_swap_b32 %0, %1" : "+v"(dw[4]), "+v"(dw[6]));
        asm("v_permlane32_swap_b32 %0, %1" : "+v"(dw[5]), "+v"(dw[7]));
        uint4v t0 = {dw[0], dw[1], dw[2], dw[3]};
        uint4v t1 = {dw[4], dw[5], dw[6], dw[7]};
        short8v pf0 = __builtin_bit_cast(short8v, t0);   // P rows n0..n0+15
        short8v pf1 = __builtin_bit_cast(short8v, t1);   // P rows n0+16..n0+31
        // PV: acc[c][m] += V'[c][n] * P[n][m]; Vf loads contiguous 1KB
        const size_t vb0 = (size_t)(nt * 2) * 8;
#pragma unroll
        for (int cb = 0; cb < 8; ++cb) {
            short8v v0 = *(const short8v*)(Vb + ((vb0 + cb) * 64 + lane) * 8);
            acc[cb] = __builtin_amdgcn_mfma_f32_32x32x16_bf16(v0, pf0, acc[cb], 0, 0, 0);
        }
#pragma unroll
        for (int cb = 0; cb < 8; ++cb) {
            short8v v1 = *(const short8v*)(Vb + ((vb0 + 8 + cb) * 64 + lane) * 8);
            acc[cb] = __builtin_amdgcn_mfma_f32_32x32x16_bf16(v1, pf1, acc[cb], 0, 0, 0);
        }
    }

    // partial colsum: lanes l and l+32 hold complementary n-halves of column m
    float csum = (csum4[0] + csum4[1]) + (csum4[2] + csum4[3]);
    csum += __shfl_xor(csum, 32);
    if (lane < 32) pcs[((size_t)ns * B_ + b) * N_ + m0 + lane] = csum;
    // partial XR out: bf16 [ns&1][b][m][c] into lo (ns<2) or hi (ns>=2) region
    unsigned short* pb = (ns < 2 ? pxr_lo + (size_t)(ns) * B_ * N_ * 256
                                 : pxr_hi + (size_t)(ns - 2) * B_ * N_ * 256)
                         + (size_t)b * N_ * 256;
    const int m = m0 + l31;
#pragma unroll
    for (int cb = 0; cb < 8; ++cb)
#pragma unroll
        for (int s = 0; s < 4; ++s) {
            short4v pk;
#pragma unroll
            for (int r = 0; r < 4; ++r) pk[r] = (short)f2bf(acc[cb][4 * s + r]);
            *(short4v*)(pb + (size_t)m * 256 + cb * 32 + 8 * s + 4 * hi) = pk;
        }
}

// ------- reduce 4 partials + diff, in place: dh[b][m][c] = bf16( xst - Σp/(1e-9+Σcs) )
__global__ __launch_bounds__(256) void reduce_diff(const unsigned short* __restrict__ pxr_lo,
                                                   const unsigned short* __restrict__ pxr_hi,
                                                   const float* __restrict__ pcs,
                                                   unsigned short* __restrict__ dh) {
    size_t i = (size_t)blockIdx.x * 256 + threadIdx.x;   // over B*N*C/8
    size_t e0 = i * 8;
    int m = (int)((e0 >> 8) & (N_ - 1));
    int b = (int)(e0 >> 20);
    const size_t S = (size_t)B_ * N_ * 256;
    float cs = pcs[(size_t)b * N_ + m] + pcs[((size_t)B_ + b) * N_ + m]
             + pcs[((size_t)2 * B_ + b) * N_ + m] + pcs[((size_t)3 * B_ + b) * N_ + m];
    float inv = 1.f / (1e-9f + cs);
    short8v p0 = *(const short8v*)(pxr_lo + e0);
    short8v p1 = *(const short8v*)(pxr_lo + S + e0);
    short8v p2 = *(const short8v*)(pxr_hi + e0);
    short8v p3 = *(const short8v*)(pxr_hi + S + e0);
    short8v xv = *(const short8v*)(dh + e0);
    short8v o;
#pragma unroll
    for (int j = 0; j < 8; ++j) {
        float xr = ((bf2f((unsigned short)p0[j]) + bf2f((unsigned short)p1[j]))
                  + (bf2f((unsigned short)p2[j]) + bf2f((unsigned short)p3[j]))) * inv;
        o[j] = (short)f2bf(bf2f((unsigned short)xv[j]) - xr);
    }
    *(short8v*)(dh + e0) = o;
}

// ------- t-conv + finalize (MFMA), 128-wide c-tile: out = xs + leaky(bn(t))
__global__ __launch_bounds__(512, 2) void convt_kernel(const unsigned short* __restrict__ dh,
                                                       const unsigned short* __restrict__ wh,
                                                       const float* __restrict__ bt,
                                                       const float* __restrict__ xs,
                                                       float* __restrict__ out,
                                                       const float* __restrict__ gam,
                                                       const float* __restrict__ bet,
                                                       const float* __restrict__ mu,
                                                       const float* __restrict__ var) {
    const int tid = threadIdx.x, wave = tid >> 6, lane = tid & 63, q = lane & 15, g = lane >> 4;
    const int m0 = blockIdx.x * 64, c0 = blockIdx.y * 128, b = blockIdx.z;
    const int cc = c0 + wave * 16;
    const unsigned short* db = dh + (size_t)b * N_ * 256;
    f32x4 acc[4];
#pragma unroll
    for (int j = 0; j < 4; ++j) acc[j] = (f32x4){0.f, 0.f, 0.f, 0.f};
    for (int ks = 0; ks < 8; ++ks) {
        short8v bw = *(const short8v*)(wh + (size_t)(cc + q) * 256 + ks * 32 + 8 * g);
#pragma unroll
        for (int j = 0; j < 4; ++j) {
            short8v ad = *(const short8v*)(db + (size_t)(m0 + j * 16 + q) * 256 + ks * 32 + 8 * g);
            acc[j] = __builtin_amdgcn_mfma_f32_16x16x32_bf16(ad, bw, acc[j], 0, 0, 0);
        }
    }
    const int c = cc + q;
    const float sc = rsqrtf(var[c] + 1e-5f) * gam[c];
    const float sh = bet[c] - mu[c] * sc;
    const float bb = bt[c];
#pragma unroll
    for (int j = 0; j < 4; ++j) {
        size_t off = ((size_t)b * C_ + c) * N_ + m0 + j * 16 + 4 * g;
        float4 xv = *(const float4*)(xs + off);
        float4 o;
        float tn;
        tn = (acc[j][0] + bb) * sc + sh; o.x = xv.x + (tn >= 0.f ? tn : 0.2f * tn);
        tn = (acc[j][1] + bb) * sc + sh; o.y = xv.y + (tn >= 0.f ? tn : 0.2f * tn);
        tn = (acc[j][2] + bb) * sc + sh; o.z = xv.z + (tn >= 0.f ? tn : 0.2f * tn);
        tn = (acc[j][3] + bb) * sc + sh; o.w = xv.w + (tn >= 0.f ? tn : 0.2f * tn);
        *(float4*)(out + off) = o;
    }
}

// ----------------------------------------------------------------------------------------
extern "C" void kernel_launch(void* const* d_in, const int* in_sizes, int n_in,
                              void* d_out, int out_size, void* d_ws, size_t ws_size,
                              hipStream_t stream) {
    (void)in_sizes; (void)n_in; (void)out_size; (void)ws_size;
    const float* x   = (const float*)d_in[0];
    const float* xyz = (const float*)d_in[1];
    const float* wqk = (const float*)d_in[2];
    const float* bqk = (const float*)d_in[3];
    const float* wv  = (const float*)d_in[4];
    const float* bv  = (const float*)d_in[5];
    const float* wt  = (const float*)d_in[6];
    const float* bt  = (const float*)d_in[7];
    const float* gam = (const float*)d_in[8];
    const float* bet = (const float*)d_in[9];
    const float* mu  = (const float*)d_in[10];
    const float* var = (const float*)d_in[11];
    float* out = (float*)d_out;

    const size_t M8 = (size_t)B_ * C_ * N_;   // 8M elements
    float* ws = (float*)d_ws;
    size_t off = 0;
    float* xs = ws + off;                              off += M8;       // fp32 [b][c][n] 32MB
    unsigned short* xst = (unsigned short*)(ws + off); off += M8 / 2;   // bf16 [b][n][c] 16MB
    unsigned short* Qf  = (unsigned short*)(ws + off); off += M8 / 8;   // bf16 frag-major 4MB
    unsigned short* Vf  = (unsigned short*)(ws + off); off += M8 / 2;   // bf16 frag-major 16MB
    unsigned short* wh  = (unsigned short*)(ws + off); off += 81920;    // bf16 weights
    float* pmax = ws + off; off += (size_t)JS_ * B_ * N_;
    float* psum = ws + off; off += (size_t)JS_ * B_ * N_;
    float* rmb  = ws + off; off += (size_t)B_ * N_;     // NEGATED row max
    float* rsb  = ws + off; off += (size_t)B_ * N_;
    float* pcs  = ws + off; off += (size_t)NSPLIT * B_ * N_;
    unsigned short* pxr_lo = (unsigned short*)(ws + off); off += M8;    // splits 0,1 (32MB)
    unsigned short* pxr_hi = (unsigned short*)out;                      // splits 2,3 in d_out
    unsigned short* dhb = xst;   // reduce_diff updates xst in place -> dh

    wcvt_kernel<<<dim3(144), dim3(256), 0, stream>>>(wqk, wv, wt, wh);
    addt_kernel<<<dim3(N_ / 64, C_ / 64, B_), dim3(256), 0, stream>>>(x, xyz, xs, xst);
    convq_kernel<<<dim3(N_ / 64, B_), dim3(256), 0, stream>>>(xst, wh, bqk, Qf);
    rowstats_mfma<<<dim3(B_ * 32 * JS_), dim3(256), 0, stream>>>(Qf, pmax, psum);
    rowmerge_kernel<<<dim3(B_ * N_ / 256), dim3(256), 0, stream>>>(pmax, psum, rmb, rsb);
    convv_kernel<<<dim3(N_ / 64, C_ / 128, B_), dim3(512), 0, stream>>>(
        xst, wh + 16384, bv, rsb, Vf);
    pv_mfma32<<<dim3(B_ * 32 * NSPLIT), dim3(256), 0, stream>>>(
        Qf, Vf, rmb, rsb, pxr_lo, pxr_hi, pcs);
    reduce_diff<<<dim3(B_ * N_ * C_ / 8 / 256), dim3(256), 0, stream>>>(
        pxr_lo, pxr_hi, pcs, dhb);
    convt_kernel<<<dim3(N_ / 64, C_ / 128, B_), dim3(512), 0, stream>>>(
        dhb, wh + 81920, bt, xs, out, gam, bet, mu, var);
}

// Round 16
// 280.366 us; speedup vs baseline: 1.1243x; 1.1243x over previous
//
#include <hip/hip_runtime.h>
#include <math.h>

#define B_   8
#define C_   256
#define N_   4096
#define CQK_ 64
#define JS_  8
#define NSPLIT 2
#define NRANGE (N_ / NSPLIT)   // 2048

// Qf is pre-scaled by sqrt(log2(e)) so q.k logits are in log2 domain: exp -> v_exp_f32.
#define SCQ 1.20110674f
#define THR2 11.54f            // defer-max threshold (8 nats in log2 units)

typedef __attribute__((ext_vector_type(8))) short short8v;    // 8 x bf16 (4 VGPRs)
typedef __attribute__((ext_vector_type(4))) short short4v;    // 4 x bf16 (8B)
typedef __attribute__((ext_vector_type(4))) float f32x4;
typedef __attribute__((ext_vector_type(16))) float f32x16;
typedef __attribute__((ext_vector_type(4))) unsigned int uint4v;

__device__ __forceinline__ unsigned short f2bf(float f) {
    unsigned u = __float_as_uint(f);
    u += 0x7fffu + ((u >> 16) & 1u);
    return (unsigned short)(u >> 16);
}
__device__ __forceinline__ float bf2f(unsigned short h) {
    return __uint_as_float((unsigned)h << 16);
}
// Single-instruction exp2 via COMPILER BUILTIN (hazard-safe; r10's raw asm broke TRANS->VALU
// wait-state insertion). r14 A/B: halves pv VALU cycles (34->19% busy).
__device__ __forceinline__ float fexp2(float x) { return __builtin_amdgcn_exp2f(x); }
// NOTE: do NOT barrier-phase-lock waves for L1 reuse (r11: no traffic cut, -140%).
// NOTE: m=64/wave spills (r12). do NOT pointer-bump/unroll-2 the pv loop (r13).
// r15: occupancy is register-capped at 2 waves/SIMD (116 VGPR + 128 AGPR acc = 244);
//      NSPLIT does not change it. pv is L2-BW bound on 4x-redundant V reads ->
//      r16: share P via LDS (write own m-chunk's P, read all 4), V sliced per wave.

// Fragment-major layouts (one wave load = contiguous 1KB):
//  Qf[b][nt(32n)][ks(16c)][lane][8]: element (n = nt*32 + (lane&31), c = ks*16 + (lane>>5)*8 + j)
//  Vf[b][nt16(16n)][cb(32c)][lane][8]: element (c = cb*32 + (lane&31), n = nt16*16 + (lane>>5)*8 + j)

// ------------------------------------------------ weights fp32 -> bf16 (row-major, packed)
__global__ __launch_bounds__(256) void wcvt_kernel(const float* __restrict__ wqk,
                                                   const float* __restrict__ wv,
                                                   const float* __restrict__ wt,
                                                   unsigned short* __restrict__ wh) {
    int i = (blockIdx.x * 256 + threadIdx.x) * 4;   // 144*256*4 = 147456 total
    const float* src; int off;
    if (i < 16384)      { src = wqk; off = i; }
    else if (i < 81920) { src = wv;  off = i - 16384; }
    else                { src = wt;  off = i - 81920; }
    float4 v = *(const float4*)(src + off);
    short4v o;
    o[0] = (short)f2bf(v.x); o[1] = (short)f2bf(v.y);
    o[2] = (short)f2bf(v.z); o[3] = (short)f2bf(v.w);
    *(short4v*)(wh + i) = o;
}

// --------------------------- xs = x + xyz (fp32 [b][c][n]) AND xst bf16 transposed [b][n][c]
__global__ __launch_bounds__(256) void addt_kernel(const float* __restrict__ x,
                                                   const float* __restrict__ xyz,
                                                   float* __restrict__ xs,
                                                   unsigned short* __restrict__ xst) {
    __shared__ float st[64][65];
    const int tid = threadIdx.x;
    const int n0 = blockIdx.x * 64, c0 = blockIdx.y * 64, b = blockIdx.z;
    const size_t base = ((size_t)b * C_ + c0) * N_ + n0;
#pragma unroll
    for (int r = 0; r < 4; ++r) {
        int c = r * 16 + (tid >> 4);
        int nc = (tid & 15) * 4;
        size_t off = base + (size_t)c * N_ + nc;
        float4 xv = *(const float4*)(x + off);
        float4 yv = *(const float4*)(xyz + off);
        float4 s = make_float4(xv.x + yv.x, xv.y + yv.y, xv.z + yv.z, xv.w + yv.w);
        *(float4*)(xs + off) = s;
        st[c][nc] = s.x; st[c][nc + 1] = s.y; st[c][nc + 2] = s.z; st[c][nc + 3] = s.w;
    }
    __syncthreads();
    int n = tid >> 2, cc = (tid & 3) * 16;
    short8v p0, p1;
#pragma unroll
    for (int j = 0; j < 8; ++j) {
        p0[j] = (short)f2bf(st[cc + j][n]);
        p1[j] = (short)f2bf(st[cc + 8 + j][n]);
    }
    size_t ob = ((size_t)b * N_ + n0 + n) * 256 + c0 + cc;
    *(short8v*)(xst + ob) = p0;
    *(short8v*)(xst + ob + 8) = p1;
}

// --------------------- Q-conv (MFMA): out Qf fragment-major, pre-scaled by SCQ (log2 domain)
__global__ __launch_bounds__(256, 4) void convq_kernel(const unsigned short* __restrict__ xst,
                                                       const unsigned short* __restrict__ wh,
                                                       const float* __restrict__ bias,
                                                       unsigned short* __restrict__ Qf) {
    const int tid = threadIdx.x, wave = tid >> 6, lane = tid & 63, q = lane & 15, g = lane >> 4;
    const int n0 = blockIdx.x * 64, b = blockIdx.y;
    const unsigned short* xb = xst + (size_t)b * N_ * 256;
    f32x4 acc[4];
#pragma unroll
    for (int j = 0; j < 4; ++j) acc[j] = (f32x4){0.f, 0.f, 0.f, 0.f};
    for (int ks = 0; ks < 8; ++ks) {
        short8v aw = *(const short8v*)(wh + (size_t)(wave * 16 + q) * 256 + ks * 32 + 8 * g);
#pragma unroll
        for (int j = 0; j < 4; ++j) {
            short8v bx = *(const short8v*)(xb + (size_t)(n0 + j * 16 + q) * 256 + ks * 32 + 8 * g);
            acc[j] = __builtin_amdgcn_mfma_f32_16x16x32_bf16(aw, bx, acc[j], 0, 0, 0);
        }
    }
    // element (n = n0+j*16+q, c = wave*16+4g+r) -> Qf[(b*128+nt)*4+ks=wave][hi=g>>1][l31][jj=4(g&1)+r]
#pragma unroll
    for (int j = 0; j < 4; ++j) {
        short4v pk;
#pragma unroll
        for (int r = 0; r < 4; ++r)
            pk[r] = (short)f2bf((acc[j][r] + bias[wave * 16 + 4 * g + r]) * SCQ);
        const int n = n0 + j * 16 + q;
        size_t a = ((((size_t)b * 128 + (n >> 5)) * 4 + wave) * 64 + (g >> 1) * 32 + (n & 31)) * 8
                   + (g & 1) * 4;
        *(short4v*)(Qf + a) = pk;
    }
}

// --------------------- V-conv (MFMA): out Vf fragment-major, PRE-SCALED by rsinv[n]
__global__ __launch_bounds__(512, 2) void convv_kernel(const unsigned short* __restrict__ xst,
                                                       const unsigned short* __restrict__ wh,
                                                       const float* __restrict__ bias,
                                                       const float* __restrict__ rsinv,
                                                       unsigned short* __restrict__ Vf) {
    const int tid = threadIdx.x, wave = tid >> 6, lane = tid & 63, q = lane & 15, g = lane >> 4;
    const int n0 = blockIdx.x * 64, o0 = blockIdx.y * 128, b = blockIdx.z;
    const int oo = o0 + wave * 16;
    const unsigned short* xb = xst + (size_t)b * N_ * 256;
    const float* rsb = rsinv + (size_t)b * N_;
    f32x4 acc[4];
#pragma unroll
    for (int j = 0; j < 4; ++j) acc[j] = (f32x4){0.f, 0.f, 0.f, 0.f};
    for (int ks = 0; ks < 8; ++ks) {
        short8v bw = *(const short8v*)(wh + (size_t)(oo + q) * 256 + ks * 32 + 8 * g);
#pragma unroll
        for (int j = 0; j < 4; ++j) {
            short8v ax = *(const short8v*)(xb + (size_t)(n0 + j * 16 + q) * 256 + ks * 32 + 8 * g);
            acc[j] = __builtin_amdgcn_mfma_f32_16x16x32_bf16(ax, bw, acc[j], 0, 0, 0);
        }
    }
    float bo = bias[oo + q];
    const int c = oo + q;
    // element (c, n = n0+j*16+4g+r) -> Vf[(b*256 + n0/16 + j)*8 + c>>5][hi=g>>1][c&31][4(g&1)+r]
#pragma unroll
    for (int j = 0; j < 4; ++j) {
        f32x4 rs4 = *(const f32x4*)(rsb + n0 + j * 16 + 4 * g);
        short4v pk;
#pragma unroll
        for (int r = 0; r < 4; ++r) pk[r] = (short)f2bf((acc[j][r] + bo) * rs4[r]);
        size_t a = ((((size_t)b * 256 + (n0 >> 4) + j) * 8 + (c >> 5)) * 64
                    + (g >> 1) * 32 + (c & 31)) * 8 + (g & 1) * 4;
        *(short4v*)(Vf + a) = pk;
    }
}

// ------------------ pass A: row softmax stats via 32x32 MFMA on Qf, log2 domain, defer-max
__global__ __launch_bounds__(256) void rowstats_mfma(const unsigned short* __restrict__ Qf,
                                                     float* __restrict__ pmax,
                                                     float* __restrict__ psum) {
    const int tid = threadIdx.x;
    const int wave = tid >> 6, lane = tid & 63, l31 = lane & 31;
    const int bid = blockIdx.x;
    const int b  = bid & 7;
    const int it = (bid >> 3) & 31;
    const int js = bid >> 8;
    const int i0 = it * 128 + wave * 32;
    const unsigned short* Qb = Qf + (size_t)b * 128 * 4 * 512;

    short8v bqi[4];   // B-frags: cols i (this wave's stat rows)
#pragma unroll
    for (int ks = 0; ks < 4; ++ks)
        bqi[ks] = *(const short8v*)(Qb + (((size_t)(i0 >> 5) * 4 + ks) * 64 + lane) * 8);

    float m = -1e30f, s = 0.f;
    const int jbeg = js * (N_ / JS_);
    for (int j0 = jbeg; j0 < jbeg + N_ / JS_; j0 += 32) {
        short8v an[4];
#pragma unroll
        for (int ks = 0; ks < 4; ++ks)
            an[ks] = *(const short8v*)(Qb + (((size_t)(j0 >> 5) * 4 + ks) * 64 + lane) * 8);
        f32x16 e;
#pragma unroll
        for (int r = 0; r < 16; ++r) e[r] = 0.f;
#pragma unroll
        for (int ks = 0; ks < 4; ++ks)
            e = __builtin_amdgcn_mfma_f32_32x32x16_bf16(an[ks], bqi[ks], e, 0, 0, 0);
        float pm = e[0];
#pragma unroll
        for (int r = 1; r < 16; ++r) pm = fmaxf(pm, e[r]);
        if (!__all(pm <= m + THR2)) {   // defer-max: rescale only on violation (rare)
            float mn = fmaxf(m, pm);
            s *= fexp2(m - mn);
            m = mn;
        }
#pragma unroll
        for (int r = 0; r < 16; ++r) s += fexp2(e[r] - m);
    }
    // merge hi/lo halves (each holds complementary j-subsets of column i = l31)
    {
        float mo = __shfl_xor(m, 32);
        float so = __shfl_xor(s, 32);
        float mn = fmaxf(m, mo);
        s = s * fexp2(m - mn) + so * fexp2(mo - mn);
        m = mn;
    }
    if (lane < 32) {
        size_t o = ((size_t)js * B_ + b) * N_ + i0 + l31;
        pmax[o] = m;
        psum[o] = s;
    }
}

// rowmerge: stores NEGATED rm (pv uses it directly as the MFMA C-init) + rsinv
__global__ __launch_bounds__(256) void rowmerge_kernel(const float* __restrict__ pmax,
                                                       const float* __restrict__ psum,
                                                       float* __restrict__ rmneg,
                                                       float* __restrict__ rsinv) {
    size_t i = (size_t)blockIdx.x * 256 + threadIdx.x;
    float m = -1e30f;
#pragma unroll
    for (int js = 0; js < JS_; ++js) m = fmaxf(m, pmax[(size_t)js * B_ * N_ + i]);
    float s = 0.f;
#pragma unroll
    for (int js = 0; js < JS_; ++js)
        s += psum[(size_t)js * B_ * N_ + i] * fexp2(pmax[(size_t)js * B_ * N_ + i] - m);
    rmneg[i] = -m;
    rsinv[i] = 1.f / s;
}

// --------- pass B: P shared via double-buffered LDS. Wave w: energy for m-chunk w (32 cols),
// publishes P B-frags to LDS; PV multiplies ALL 4 m-chunks' P by w's 64-channel V slice.
// Cuts per-wave L2 traffic 20KB->8KB/iter (was 4x-redundant V reads, the r15 bottleneck).
__global__ __launch_bounds__(256, 2) void pv_mfma32(const unsigned short* __restrict__ Qf,
                                                    const unsigned short* __restrict__ Vf,
                                                    const float* __restrict__ rmneg,
                                                    const float* __restrict__ rsinv,
                                                    unsigned short* __restrict__ pxr,
                                                    float* __restrict__ pcs) {
    __shared__ unsigned short Pl[2][4][2][64][8];   // [buf][mchunk][nhalf][lane][8] = 16KB
    const int tid = threadIdx.x;
    const int wave = tid >> 6, lane = tid & 63, l31 = lane & 31, hi = lane >> 5;
    const int bid = blockIdx.x;
    const int b  = bid & 7;                 // XCD-pinned: one batch per XCD
    const int mc = (bid >> 3) & 31;
    const int ns = bid >> 8;
    const int m0 = mc * 128;                // block m-tile 128; wave's energy chunk = m0+wave*32
    const int nbeg = ns * NRANGE;
    const unsigned short* Qb = Qf + (size_t)b * 128 * 4 * 512;
    const unsigned short* Vb = Vf + (size_t)b * 256 * 8 * 512;
    const float* rmb = rmneg + (size_t)b * N_;
    const float* rsb = rsinv + (size_t)b * N_;

    // persistent energy B-frags for THIS wave's m-chunk: m = m0 + wave*32 + l31
    short8v bqm[4];
#pragma unroll
    for (int ks = 0; ks < 4; ++ks)
        bqm[ks] = *(const short8v*)(Qb + (((size_t)((m0 >> 5) + wave) * 4 + ks) * 64 + lane) * 8);

    f32x16 acc[4][2];   // [mchunk][cb]: m = m0+mk*32+l31, c = (wave*2+cb)*32 + 8s+4hi+r
#pragma unroll
    for (int mk = 0; mk < 4; ++mk)
#pragma unroll
        for (int cb = 0; cb < 2; ++cb)
#pragma unroll
            for (int r = 0; r < 16; ++r) acc[mk][cb][r] = 0.f;
    f32x4 csum4 = {0.f, 0.f, 0.f, 0.f};

#pragma unroll 1
    for (int it = 0; it < NRANGE / 32; ++it) {
        const int n0 = nbeg + it * 32;
        const int nt = n0 >> 5;
        const int cur = it & 1;
        // Q A-frags (rows n) — contiguous 1KB each, L2-hot
        short8v an[4];
#pragma unroll
        for (int ks = 0; ks < 4; ++ks)
            an[ks] = *(const short8v*)(Qb + (((size_t)nt * 4 + ks) * 64 + lane) * 8);
        // stats: reg r+4s -> n = n0 + 8s + 4hi + r
        f32x4 rmn[4], rs[4];
#pragma unroll
        for (int s = 0; s < 4; ++s) {
            rmn[s] = *(const f32x4*)(rmb + n0 + 8 * s + 4 * hi);
            rs[s]  = *(const f32x4*)(rsb + n0 + 8 * s + 4 * hi);
        }
        // energy for own m-chunk: C-init = -rm (free subtraction), 4 chained k-steps
        f32x16 e;
#pragma unroll
        for (int s = 0; s < 4; ++s) {
            e[4 * s + 0] = rmn[s][0]; e[4 * s + 1] = rmn[s][1];
            e[4 * s + 2] = rmn[s][2]; e[4 * s + 3] = rmn[s][3];
        }
#pragma unroll
        for (int ks = 0; ks < 4; ++ks)
            e = __builtin_amdgcn_mfma_f32_32x32x16_bf16(an[ks], bqm[ks], e, 0, 0, 0);
        // exp2 + csum + pack to bf16 dword pairs
        unsigned dw[8];
#pragma unroll
        for (int s = 0; s < 4; ++s) {
            float p0 = fexp2(e[4 * s + 0]);
            float p1 = fexp2(e[4 * s + 1]);
            float p2 = fexp2(e[4 * s + 2]);
            float p3 = fexp2(e[4 * s + 3]);
            csum4[s] += (p0 * rs[s][0] + p1 * rs[s][1]) + (p2 * rs[s][2] + p3 * rs[s][3]);
            asm("v_cvt_pk_bf16_f32 %0, %1, %2" : "=v"(dw[2 * s + 0]) : "v"(p0), "v"(p1));
            asm("v_cvt_pk_bf16_f32 %0, %1, %2" : "=v"(dw[2 * s + 1]) : "v"(p2), "v"(p3));
        }
        // lane-half exchange -> exact PV B-frag words for own m-chunk
        asm("v_permlane32_swap_b32 %0, %1" : "+v"(dw[0]), "+v"(dw[2]));
        asm("v_permlane32_swap_b32 %0, %1" : "+v"(dw[1]), "+v"(dw[3]));
        asm("v_permlane32_swap_b32 %0, %1" : "+v"(dw[4]), "+v"(dw[6]));
        asm("v_permlane32_swap_b32 %0, %1" : "+v"(dw[5]), "+v"(dw[7]));
        uint4v t0 = {dw[0], dw[1], dw[2], dw[3]};   // P rows n0..n0+15
        uint4v t1 = {dw[4], dw[5], dw[6], dw[7]};   // P rows n0+16..n0+31
        // publish own P to LDS (double-buffered; one barrier/iter, race-safe)
        *(uint4v*)&Pl[cur][wave][0][lane][0] = t0;
        *(uint4v*)&Pl[cur][wave][1][lane][0] = t1;
        __syncthreads();
        // PV: all 4 m-chunks' P x own 64-channel V slice (V from L2, issued post-barrier)
        const size_t vb0 = (size_t)(nt * 2) * 8;
#pragma unroll
        for (int nh = 0; nh < 2; ++nh) {
            short8v v0 = *(const short8v*)(Vb + ((vb0 + nh * 8 + wave * 2 + 0) * 64 + lane) * 8);
            short8v v1 = *(const short8v*)(Vb + ((vb0 + nh * 8 + wave * 2 + 1) * 64 + lane) * 8);
#pragma unroll
            for (int mk = 0; mk < 4; ++mk) {
                short8v pf = *(const short8v*)&Pl[cur][mk][nh][lane][0];
                acc[mk][0] = __builtin_amdgcn_mfma_f32_32x32x16_bf16(v0, pf, acc[mk][0], 0, 0, 0);
                acc[mk][1] = __builtin_amdgcn_mfma_f32_32x32x16_bf16(v1, pf, acc[mk][1], 0, 0, 0);
            }
        }
    }

    // partial colsum for own m-chunk: lanes l and l+32 hold complementary n-halves
    float csum = (csum4[0] + csum4[1]) + (csum4[2] + csum4[3]);
    csum += __shfl_xor(csum, 32);
    if (lane < 32) pcs[((size_t)ns * B_ + b) * N_ + m0 + wave * 32 + l31] = csum;
    // partial XR out: bf16 [ns][b][m][c]; m = m0+mk*32+l31, c = (wave*2+cb)*32 + 8s + 4hi + r
    unsigned short* pb = pxr + ((size_t)ns * B_ + b) * N_ * 256;
#pragma unroll
    for (int mk = 0; mk < 4; ++mk) {
        const int m = m0 + mk * 32 + l31;
#pragma unroll
        for (int cb = 0; cb < 2; ++cb)
#pragma unroll
            for (int s = 0; s < 4; ++s) {
                short4v pk;
#pragma unroll
                for (int r = 0; r < 4; ++r) pk[r] = (short)f2bf(acc[mk][cb][4 * s + r]);
                *(short4v*)(pb + (size_t)m * 256 + (wave * 2 + cb) * 32 + 8 * s + 4 * hi) = pk;
            }
    }
}

// ------- reduce partials + diff, in place: dh[b][m][c] = bf16( xst - (p0+p1)/(1e-9+cs) )
__global__ __launch_bounds__(256) void reduce_diff(const unsigned short* __restrict__ pxr,
                                                   const float* __restrict__ pcs,
                                                   unsigned short* __restrict__ dh) {
    size_t i = (size_t)blockIdx.x * 256 + threadIdx.x;   // over B*N*C/8
    size_t e0 = i * 8;
    int m = (int)((e0 >> 8) & (N_ - 1));
    int b = (int)(e0 >> 20);
    float cs = pcs[(size_t)b * N_ + m] + pcs[((size_t)B_ + b) * N_ + m];
    float inv = 1.f / (1e-9f + cs);
    short8v p0 = *(const short8v*)(pxr + e0);
    short8v p1 = *(const short8v*)(pxr + (size_t)B_ * N_ * 256 + e0);
    short8v xv = *(const short8v*)(dh + e0);
    short8v o;
#pragma unroll
    for (int j = 0; j < 8; ++j) {
        float xr = (bf2f((unsigned short)p0[j]) + bf2f((unsigned short)p1[j])) * inv;
        o[j] = (short)f2bf(bf2f((unsigned short)xv[j]) - xr);
    }
    *(short8v*)(dh + e0) = o;
}

// ------- t-conv + finalize (MFMA), 128-wide c-tile: out = xs + leaky(bn(t))
__global__ __launch_bounds__(512, 2) void convt_kernel(const unsigned short* __restrict__ dh,
                                                       const unsigned short* __restrict__ wh,
                                                       const float* __restrict__ bt,
                                                       const float* __restrict__ xs,
                                                       float* __restrict__ out,
                                                       const float* __restrict__ gam,
                                                       const float* __restrict__ bet,
                                                       const float* __restrict__ mu,
                                                       const float* __restrict__ var) {
    const int tid = threadIdx.x, wave = tid >> 6, lane = tid & 63, q = lane & 15, g = lane >> 4;
    const int m0 = blockIdx.x * 64, c0 = blockIdx.y * 128, b = blockIdx.z;
    const int cc = c0 + wave * 16;
    const unsigned short* db = dh + (size_t)b * N_ * 256;
    f32x4 acc[4];
#pragma unroll
    for (int j = 0; j < 4; ++j) acc[j] = (f32x4){0.f, 0.f, 0.f, 0.f};
    for (int ks = 0; ks < 8; ++ks) {
        short8v bw = *(const short8v*)(wh + (size_t)(cc + q) * 256 + ks * 32 + 8 * g);
#pragma unroll
        for (int j = 0; j < 4; ++j) {
            short8v ad = *(const short8v*)(db + (size_t)(m0 + j * 16 + q) * 256 + ks * 32 + 8 * g);
            acc[j] = __builtin_amdgcn_mfma_f32_16x16x32_bf16(ad, bw, acc[j], 0, 0, 0);
        }
    }
    const int c = cc + q;
    const float sc = rsqrtf(var[c] + 1e-5f) * gam[c];
    const float sh = bet[c] - mu[c] * sc;
    const float bb = bt[c];
#pragma unroll
    for (int j = 0; j < 4; ++j) {
        size_t off = ((size_t)b * C_ + c) * N_ + m0 + j * 16 + 4 * g;
        float4 xv = *(const float4*)(xs + off);
        float4 o;
        float tn;
        tn = (acc[j][0] + bb) * sc + sh; o.x = xv.x + (tn >= 0.f ? tn : 0.2f * tn);
        tn = (acc[j][1] + bb) * sc + sh; o.y = xv.y + (tn >= 0.f ? tn : 0.2f * tn);
        tn = (acc[j][2] + bb) * sc + sh; o.z = xv.z + (tn >= 0.f ? tn : 0.2f * tn);
        tn = (acc[j][3] + bb) * sc + sh; o.w = xv.w + (tn >= 0.f ? tn : 0.2f * tn);
        *(float4*)(out + off) = o;
    }
}

// ----------------------------------------------------------------------------------------
extern "C" void kernel_launch(void* const* d_in, const int* in_sizes, int n_in,
                              void* d_out, int out_size, void* d_ws, size_t ws_size,
                              hipStream_t stream) {
    (void)in_sizes; (void)n_in; (void)out_size; (void)ws_size;
    const float* x   = (const float*)d_in[0];
    const float* xyz = (const float*)d_in[1];
    const float* wqk = (const float*)d_in[2];
    const float* bqk = (const float*)d_in[3];
    const float* wv  = (const float*)d_in[4];
    const float* bv  = (const float*)d_in[5];
    const float* wt  = (const float*)d_in[6];
    const float* bt  = (const float*)d_in[7];
    const float* gam = (const float*)d_in[8];
    const float* bet = (const float*)d_in[9];
    const float* mu  = (const float*)d_in[10];
    const float* var = (const float*)d_in[11];
    float* out = (float*)d_out;

    const size_t M8 = (size_t)B_ * C_ * N_;   // 8M elements
    float* ws = (float*)d_ws;
    size_t off = 0;
    float* xs = ws + off;                              off += M8;       // fp32 [b][c][n] 32MB
    unsigned short* xst = (unsigned short*)(ws + off); off += M8 / 2;   // bf16 [b][n][c] 16MB
    unsigned short* Qf  = (unsigned short*)(ws + off); off += M8 / 8;   // bf16 frag-major 4MB
    unsigned short* Vf  = (unsigned short*)(ws + off); off += M8 / 2;   // bf16 frag-major 16MB
    unsigned short* wh  = (unsigned short*)(ws + off); off += 81920;    // bf16 weights
    float* pmax = ws + off; off += (size_t)JS_ * B_ * N_;
    float* psum = ws + off; off += (size_t)JS_ * B_ * N_;
    float* rmb  = ws + off; off += (size_t)B_ * N_;     // NEGATED row max
    float* rsb  = ws + off; off += (size_t)B_ * N_;
    float* pcs  = ws + off; off += (size_t)NSPLIT * B_ * N_;
    unsigned short* pxr = (unsigned short*)(ws + off); off += M8;       // bf16 [2][b][m][c] 32MB
    unsigned short* dhb = xst;   // reduce_diff updates xst in place -> dh

    wcvt_kernel<<<dim3(144), dim3(256), 0, stream>>>(wqk, wv, wt, wh);
    addt_kernel<<<dim3(N_ / 64, C_ / 64, B_), dim3(256), 0, stream>>>(x, xyz, xs, xst);
    convq_kernel<<<dim3(N_ / 64, B_), dim3(256), 0, stream>>>(xst, wh, bqk, Qf);
    rowstats_mfma<<<dim3(B_ * 32 * JS_), dim3(256), 0, stream>>>(Qf, pmax, psum);
    rowmerge_kernel<<<dim3(B_ * N_ / 256), dim3(256), 0, stream>>>(pmax, psum, rmb, rsb);
    convv_kernel<<<dim3(N_ / 64, C_ / 128, B_), dim3(512), 0, stream>>>(
        xst, wh + 16384, bv, rsb, Vf);
    pv_mfma32<<<dim3(B_ * 32 * NSPLIT), dim3(256), 0, stream>>>(Qf, Vf, rmb, rsb, pxr, pcs);
    reduce_diff<<<dim3(B_ * N_ * C_ / 8 / 256), dim3(256), 0, stream>>>(pxr, pcs, dhb);
    convt_kernel<<<dim3(N_ / 64, C_ / 128, B_), dim3(512), 0, stream>>>(
        dhb, wh + 81920, bt, xs, out, gam, bet, mu, var);
}

// Round 17
// 269.300 us; speedup vs baseline: 1.1705x; 1.0411x over previous
//
#include <hip/hip_runtime.h>
#include <math.h>

#define B_   8
#define C_   256
#define N_   4096
#define CQK_ 64
#define JS_  8
#define NSPLIT 2
#define NRANGE (N_ / NSPLIT)   // 2048

// Qf is pre-scaled by sqrt(log2(e)) so q.k logits are in log2 domain: exp -> v_exp_f32.
#define SCQ 1.20110674f
#define THR2 11.54f            // defer-max threshold (8 nats in log2 units)

typedef __attribute__((ext_vector_type(8))) short short8v;    // 8 x bf16 (4 VGPRs)
typedef __attribute__((ext_vector_type(4))) short short4v;    // 4 x bf16 (8B)
typedef __attribute__((ext_vector_type(4))) float f32x4;
typedef __attribute__((ext_vector_type(16))) float f32x16;
typedef __attribute__((ext_vector_type(4))) unsigned int uint4v;

__device__ __forceinline__ unsigned short f2bf(float f) {
    unsigned u = __float_as_uint(f);
    u += 0x7fffu + ((u >> 16) & 1u);
    return (unsigned short)(u >> 16);
}
__device__ __forceinline__ float bf2f(unsigned short h) {
    return __uint_as_float((unsigned)h << 16);
}
// Single-instruction exp2 via COMPILER BUILTIN (hazard-safe; r10's raw asm broke TRANS->VALU
// wait-state insertion). r14 A/B: halves pv VALU cycles (34->19% busy).
__device__ __forceinline__ float fexp2(float x) { return __builtin_amdgcn_exp2f(x); }
// NOTE: do NOT barrier-phase-lock waves for L1 reuse (r11). m=64/wave spills (r12).
// NOTE: do NOT pointer-bump/unroll-2 the pv loop (r13: load schedule destroyed).
// r15: occupancy register-capped at 2 waves/SIMD (VGPR+128 AGPR acc); NSPLIT can't change it.
// r16: P shared via LDS (-2.5x V traffic) = 158->130us. r17: hoist V loads above the barrier
//      (they don't depend on P) so their L2 latency hides under energy+exp+barrier-wait.

// Fragment-major layouts (one wave load = contiguous 1KB):
//  Qf[b][nt(32n)][ks(16c)][lane][8]: element (n = nt*32 + (lane&31), c = ks*16 + (lane>>5)*8 + j)
//  Vf[b][nt16(16n)][cb(32c)][lane][8]: element (c = cb*32 + (lane&31), n = nt16*16 + (lane>>5)*8 + j)

// ------------------------------------------------ weights fp32 -> bf16 (row-major, packed)
__global__ __launch_bounds__(256) void wcvt_kernel(const float* __restrict__ wqk,
                                                   const float* __restrict__ wv,
                                                   const float* __restrict__ wt,
                                                   unsigned short* __restrict__ wh) {
    int i = (blockIdx.x * 256 + threadIdx.x) * 4;   // 144*256*4 = 147456 total
    const float* src; int off;
    if (i < 16384)      { src = wqk; off = i; }
    else if (i < 81920) { src = wv;  off = i - 16384; }
    else                { src = wt;  off = i - 81920; }
    float4 v = *(const float4*)(src + off);
    short4v o;
    o[0] = (short)f2bf(v.x); o[1] = (short)f2bf(v.y);
    o[2] = (short)f2bf(v.z); o[3] = (short)f2bf(v.w);
    *(short4v*)(wh + i) = o;
}

// --------------------------- xs = x + xyz (fp32 [b][c][n]) AND xst bf16 transposed [b][n][c]
__global__ __launch_bounds__(256) void addt_kernel(const float* __restrict__ x,
                                                   const float* __restrict__ xyz,
                                                   float* __restrict__ xs,
                                                   unsigned short* __restrict__ xst) {
    __shared__ float st[64][65];
    const int tid = threadIdx.x;
    const int n0 = blockIdx.x * 64, c0 = blockIdx.y * 64, b = blockIdx.z;
    const size_t base = ((size_t)b * C_ + c0) * N_ + n0;
#pragma unroll
    for (int r = 0; r < 4; ++r) {
        int c = r * 16 + (tid >> 4);
        int nc = (tid & 15) * 4;
        size_t off = base + (size_t)c * N_ + nc;
        float4 xv = *(const float4*)(x + off);
        float4 yv = *(const float4*)(xyz + off);
        float4 s = make_float4(xv.x + yv.x, xv.y + yv.y, xv.z + yv.z, xv.w + yv.w);
        *(float4*)(xs + off) = s;
        st[c][nc] = s.x; st[c][nc + 1] = s.y; st[c][nc + 2] = s.z; st[c][nc + 3] = s.w;
    }
    __syncthreads();
    int n = tid >> 2, cc = (tid & 3) * 16;
    short8v p0, p1;
#pragma unroll
    for (int j = 0; j < 8; ++j) {
        p0[j] = (short)f2bf(st[cc + j][n]);
        p1[j] = (short)f2bf(st[cc + 8 + j][n]);
    }
    size_t ob = ((size_t)b * N_ + n0 + n) * 256 + c0 + cc;
    *(short8v*)(xst + ob) = p0;
    *(short8v*)(xst + ob + 8) = p1;
}

// --------------------- Q-conv (MFMA): out Qf fragment-major, pre-scaled by SCQ (log2 domain)
__global__ __launch_bounds__(256, 4) void convq_kernel(const unsigned short* __restrict__ xst,
                                                       const unsigned short* __restrict__ wh,
                                                       const float* __restrict__ bias,
                                                       unsigned short* __restrict__ Qf) {
    const int tid = threadIdx.x, wave = tid >> 6, lane = tid & 63, q = lane & 15, g = lane >> 4;
    const int n0 = blockIdx.x * 64, b = blockIdx.y;
    const unsigned short* xb = xst + (size_t)b * N_ * 256;
    f32x4 acc[4];
#pragma unroll
    for (int j = 0; j < 4; ++j) acc[j] = (f32x4){0.f, 0.f, 0.f, 0.f};
    for (int ks = 0; ks < 8; ++ks) {
        short8v aw = *(const short8v*)(wh + (size_t)(wave * 16 + q) * 256 + ks * 32 + 8 * g);
#pragma unroll
        for (int j = 0; j < 4; ++j) {
            short8v bx = *(const short8v*)(xb + (size_t)(n0 + j * 16 + q) * 256 + ks * 32 + 8 * g);
            acc[j] = __builtin_amdgcn_mfma_f32_16x16x32_bf16(aw, bx, acc[j], 0, 0, 0);
        }
    }
    // element (n = n0+j*16+q, c = wave*16+4g+r) -> Qf[(b*128+nt)*4+ks=wave][hi=g>>1][l31][jj=4(g&1)+r]
#pragma unroll
    for (int j = 0; j < 4; ++j) {
        short4v pk;
#pragma unroll
        for (int r = 0; r < 4; ++r)
            pk[r] = (short)f2bf((acc[j][r] + bias[wave * 16 + 4 * g + r]) * SCQ);
        const int n = n0 + j * 16 + q;
        size_t a = ((((size_t)b * 128 + (n >> 5)) * 4 + wave) * 64 + (g >> 1) * 32 + (n & 31)) * 8
                   + (g & 1) * 4;
        *(short4v*)(Qf + a) = pk;
    }
}

// --------------------- V-conv (MFMA): out Vf fragment-major, PRE-SCALED by rsinv[n]
__global__ __launch_bounds__(512, 2) void convv_kernel(const unsigned short* __restrict__ xst,
                                                       const unsigned short* __restrict__ wh,
                                                       const float* __restrict__ bias,
                                                       const float* __restrict__ rsinv,
                                                       unsigned short* __restrict__ Vf) {
    const int tid = threadIdx.x, wave = tid >> 6, lane = tid & 63, q = lane & 15, g = lane >> 4;
    const int n0 = blockIdx.x * 64, o0 = blockIdx.y * 128, b = blockIdx.z;
    const int oo = o0 + wave * 16;
    const unsigned short* xb = xst + (size_t)b * N_ * 256;
    const float* rsb = rsinv + (size_t)b * N_;
    f32x4 acc[4];
#pragma unroll
    for (int j = 0; j < 4; ++j) acc[j] = (f32x4){0.f, 0.f, 0.f, 0.f};
    for (int ks = 0; ks < 8; ++ks) {
        short8v bw = *(const short8v*)(wh + (size_t)(oo + q) * 256 + ks * 32 + 8 * g);
#pragma unroll
        for (int j = 0; j < 4; ++j) {
            short8v ax = *(const short8v*)(xb + (size_t)(n0 + j * 16 + q) * 256 + ks * 32 + 8 * g);
            acc[j] = __builtin_amdgcn_mfma_f32_16x16x32_bf16(ax, bw, acc[j], 0, 0, 0);
        }
    }
    float bo = bias[oo + q];
    const int c = oo + q;
    // element (c, n = n0+j*16+4g+r) -> Vf[(b*256 + n0/16 + j)*8 + c>>5][hi=g>>1][c&31][4(g&1)+r]
#pragma unroll
    for (int j = 0; j < 4; ++j) {
        f32x4 rs4 = *(const f32x4*)(rsb + n0 + j * 16 + 4 * g);
        short4v pk;
#pragma unroll
        for (int r = 0; r < 4; ++r) pk[r] = (short)f2bf((acc[j][r] + bo) * rs4[r]);
        size_t a = ((((size_t)b * 256 + (n0 >> 4) + j) * 8 + (c >> 5)) * 64
                    + (g >> 1) * 32 + (c & 31)) * 8 + (g & 1) * 4;
        *(short4v*)(Vf + a) = pk;
    }
}

// ------------------ pass A: row softmax stats via 32x32 MFMA on Qf, log2 domain, defer-max
__global__ __launch_bounds__(256) void rowstats_mfma(const unsigned short* __restrict__ Qf,
                                                     float* __restrict__ pmax,
                                                     float* __restrict__ psum) {
    const int tid = threadIdx.x;
    const int wave = tid >> 6, lane = tid & 63, l31 = lane & 31;
    const int bid = blockIdx.x;
    const int b  = bid & 7;
    const int it = (bid >> 3) & 31;
    const int js = bid >> 8;
    const int i0 = it * 128 + wave * 32;
    const unsigned short* Qb = Qf + (size_t)b * 128 * 4 * 512;

    short8v bqi[4];   // B-frags: cols i (this wave's stat rows)
#pragma unroll
    for (int ks = 0; ks < 4; ++ks)
        bqi[ks] = *(const short8v*)(Qb + (((size_t)(i0 >> 5) * 4 + ks) * 64 + lane) * 8);

    float m = -1e30f, s = 0.f;
    const int jbeg = js * (N_ / JS_);
    for (int j0 = jbeg; j0 < jbeg + N_ / JS_; j0 += 32) {
        short8v an[4];
#pragma unroll
        for (int ks = 0; ks < 4; ++ks)
            an[ks] = *(const short8v*)(Qb + (((size_t)(j0 >> 5) * 4 + ks) * 64 + lane) * 8);
        f32x16 e;
#pragma unroll
        for (int r = 0; r < 16; ++r) e[r] = 0.f;
#pragma unroll
        for (int ks = 0; ks < 4; ++ks)
            e = __builtin_amdgcn_mfma_f32_32x32x16_bf16(an[ks], bqi[ks], e, 0, 0, 0);
        float pm = e[0];
#pragma unroll
        for (int r = 1; r < 16; ++r) pm = fmaxf(pm, e[r]);
        if (!__all(pm <= m + THR2)) {   // defer-max: rescale only on violation (rare)
            float mn = fmaxf(m, pm);
            s *= fexp2(m - mn);
            m = mn;
        }
#pragma unroll
        for (int r = 0; r < 16; ++r) s += fexp2(e[r] - m);
    }
    // merge hi/lo halves (each holds complementary j-subsets of column i = l31)
    {
        float mo = __shfl_xor(m, 32);
        float so = __shfl_xor(s, 32);
        float mn = fmaxf(m, mo);
        s = s * fexp2(m - mn) + so * fexp2(mo - mn);
        m = mn;
    }
    if (lane < 32) {
        size_t o = ((size_t)js * B_ + b) * N_ + i0 + l31;
        pmax[o] = m;
        psum[o] = s;
    }
}

// rowmerge: stores NEGATED rm (pv uses it directly as the MFMA C-init) + rsinv
__global__ __launch_bounds__(256) void rowmerge_kernel(const float* __restrict__ pmax,
                                                       const float* __restrict__ psum,
                                                       float* __restrict__ rmneg,
                                                       float* __restrict__ rsinv) {
    size_t i = (size_t)blockIdx.x * 256 + threadIdx.x;
    float m = -1e30f;
#pragma unroll
    for (int js = 0; js < JS_; ++js) m = fmaxf(m, pmax[(size_t)js * B_ * N_ + i]);
    float s = 0.f;
#pragma unroll
    for (int js = 0; js < JS_; ++js)
        s += psum[(size_t)js * B_ * N_ + i] * fexp2(pmax[(size_t)js * B_ * N_ + i] - m);
    rmneg[i] = -m;
    rsinv[i] = 1.f / s;
}

// --------- pass B: P shared via double-buffered LDS (r16). V-slice loads hoisted ABOVE the
// barrier (no P dependence) so L2 latency hides under energy+exp+barrier-wait. setprio on PV.
__global__ __launch_bounds__(256, 2) void pv_mfma32(const unsigned short* __restrict__ Qf,
                                                    const unsigned short* __restrict__ Vf,
                                                    const float* __restrict__ rmneg,
                                                    const float* __restrict__ rsinv,
                                                    unsigned short* __restrict__ pxr,
                                                    float* __restrict__ pcs) {
    __shared__ unsigned short Pl[2][4][2][64][8];   // [buf][mchunk][nhalf][lane][8] = 16KB
    const int tid = threadIdx.x;
    const int wave = tid >> 6, lane = tid & 63, l31 = lane & 31, hi = lane >> 5;
    const int bid = blockIdx.x;
    const int b  = bid & 7;                 // XCD-pinned: one batch per XCD
    const int mc = (bid >> 3) & 31;
    const int ns = bid >> 8;
    const int m0 = mc * 128;                // block m-tile 128; wave's energy chunk = m0+wave*32
    const int nbeg = ns * NRANGE;
    const unsigned short* Qb = Qf + (size_t)b * 128 * 4 * 512;
    const unsigned short* Vb = Vf + (size_t)b * 256 * 8 * 512;
    const float* rmb = rmneg + (size_t)b * N_;
    const float* rsb = rsinv + (size_t)b * N_;

    // persistent energy B-frags for THIS wave's m-chunk: m = m0 + wave*32 + l31
    short8v bqm[4];
#pragma unroll
    for (int ks = 0; ks < 4; ++ks)
        bqm[ks] = *(const short8v*)(Qb + (((size_t)((m0 >> 5) + wave) * 4 + ks) * 64 + lane) * 8);

    f32x16 acc[4][2];   // [mchunk][cb]: m = m0+mk*32+l31, c = (wave*2+cb)*32 + 8s+4hi+r
#pragma unroll
    for (int mk = 0; mk < 4; ++mk)
#pragma unroll
        for (int cb = 0; cb < 2; ++cb)
#pragma unroll
            for (int r = 0; r < 16; ++r) acc[mk][cb][r] = 0.f;
    f32x4 csum4 = {0.f, 0.f, 0.f, 0.f};

#pragma unroll 1
    for (int it = 0; it < NRANGE / 32; ++it) {
        const int n0 = nbeg + it * 32;
        const int nt = n0 >> 5;
        const int cur = it & 1;
        // V-slice loads FIRST (consumed after the barrier; latency hides under energy+exp)
        const size_t vb0 = (size_t)(nt * 2) * 8;
        short8v vreg[2][2];
#pragma unroll
        for (int nh = 0; nh < 2; ++nh) {
            vreg[nh][0] = *(const short8v*)(Vb + ((vb0 + nh * 8 + wave * 2 + 0) * 64 + lane) * 8);
            vreg[nh][1] = *(const short8v*)(Vb + ((vb0 + nh * 8 + wave * 2 + 1) * 64 + lane) * 8);
        }
        // Q A-frags (rows n) — contiguous 1KB each, L2-hot
        short8v an[4];
#pragma unroll
        for (int ks = 0; ks < 4; ++ks)
            an[ks] = *(const short8v*)(Qb + (((size_t)nt * 4 + ks) * 64 + lane) * 8);
        // stats: reg r+4s -> n = n0 + 8s + 4hi + r
        f32x4 rmn[4], rs[4];
#pragma unroll
        for (int s = 0; s < 4; ++s) {
            rmn[s] = *(const f32x4*)(rmb + n0 + 8 * s + 4 * hi);
            rs[s]  = *(const f32x4*)(rsb + n0 + 8 * s + 4 * hi);
        }
        // energy for own m-chunk: C-init = -rm (free subtraction), 4 chained k-steps
        f32x16 e;
#pragma unroll
        for (int s = 0; s < 4; ++s) {
            e[4 * s + 0] = rmn[s][0]; e[4 * s + 1] = rmn[s][1];
            e[4 * s + 2] = rmn[s][2]; e[4 * s + 3] = rmn[s][3];
        }
#pragma unroll
        for (int ks = 0; ks < 4; ++ks)
            e = __builtin_amdgcn_mfma_f32_32x32x16_bf16(an[ks], bqm[ks], e, 0, 0, 0);
        // exp2 + csum + pack to bf16 dword pairs
        unsigned dw[8];
#pragma unroll
        for (int s = 0; s < 4; ++s) {
            float p0 = fexp2(e[4 * s + 0]);
            float p1 = fexp2(e[4 * s + 1]);
            float p2 = fexp2(e[4 * s + 2]);
            float p3 = fexp2(e[4 * s + 3]);
            csum4[s] += (p0 * rs[s][0] + p1 * rs[s][1]) + (p2 * rs[s][2] + p3 * rs[s][3]);
            asm("v_cvt_pk_bf16_f32 %0, %1, %2" : "=v"(dw[2 * s + 0]) : "v"(p0), "v"(p1));
            asm("v_cvt_pk_bf16_f32 %0, %1, %2" : "=v"(dw[2 * s + 1]) : "v"(p2), "v"(p3));
        }
        // lane-half exchange -> exact PV B-frag words for own m-chunk
        asm("v_permlane32_swap_b32 %0, %1" : "+v"(dw[0]), "+v"(dw[2]));
        asm("v_permlane32_swap_b32 %0, %1" : "+v"(dw[1]), "+v"(dw[3]));
        asm("v_permlane32_swap_b32 %0, %1" : "+v"(dw[4]), "+v"(dw[6]));
        asm("v_permlane32_swap_b32 %0, %1" : "+v"(dw[5]), "+v"(dw[7]));
        uint4v t0 = {dw[0], dw[1], dw[2], dw[3]};   // P rows n0..n0+15
        uint4v t1 = {dw[4], dw[5], dw[6], dw[7]};   // P rows n0+16..n0+31
        // publish own P to LDS (double-buffered; one barrier/iter, race-safe)
        *(uint4v*)&Pl[cur][wave][0][lane][0] = t0;
        *(uint4v*)&Pl[cur][wave][1][lane][0] = t1;
        __syncthreads();
        // PV: all 4 m-chunks' P x own 64-channel V slice (V already in registers)
        __builtin_amdgcn_s_setprio(1);
#pragma unroll
        for (int nh = 0; nh < 2; ++nh) {
#pragma unroll
            for (int mk = 0; mk < 4; ++mk) {
                short8v pf = *(const short8v*)&Pl[cur][mk][nh][lane][0];
                acc[mk][0] = __builtin_amdgcn_mfma_f32_32x32x16_bf16(vreg[nh][0], pf,
                                                                     acc[mk][0], 0, 0, 0);
                acc[mk][1] = __builtin_amdgcn_mfma_f32_32x32x16_bf16(vreg[nh][1], pf,
                                                                     acc[mk][1], 0, 0, 0);
            }
        }
        __builtin_amdgcn_s_setprio(0);
    }

    // partial colsum for own m-chunk: lanes l and l+32 hold complementary n-halves
    float csum = (csum4[0] + csum4[1]) + (csum4[2] + csum4[3]);
    csum += __shfl_xor(csum, 32);
    if (lane < 32) pcs[((size_t)ns * B_ + b) * N_ + m0 + wave * 32 + l31] = csum;
    // partial XR out: bf16 [ns][b][m][c]; m = m0+mk*32+l31, c = (wave*2+cb)*32 + 8s + 4hi + r
    unsigned short* pb = pxr + ((size_t)ns * B_ + b) * N_ * 256;
#pragma unroll
    for (int mk = 0; mk < 4; ++mk) {
        const int m = m0 + mk * 32 + l31;
#pragma unroll
        for (int cb = 0; cb < 2; ++cb)
#pragma unroll
            for (int s = 0; s < 4; ++s) {
                short4v pk;
#pragma unroll
                for (int r = 0; r < 4; ++r) pk[r] = (short)f2bf(acc[mk][cb][4 * s + r]);
                *(short4v*)(pb + (size_t)m * 256 + (wave * 2 + cb) * 32 + 8 * s + 4 * hi) = pk;
            }
    }
}

// ------- reduce partials + diff, in place: dh[b][m][c] = bf16( xst - (p0+p1)/(1e-9+cs) )
__global__ __launch_bounds__(256) void reduce_diff(const unsigned short* __restrict__ pxr,
                                                   const float* __restrict__ pcs,
                                                   unsigned short* __restrict__ dh) {
    size_t i = (size_t)blockIdx.x * 256 + threadIdx.x;   // over B*N*C/8
    size_t e0 = i * 8;
    int m = (int)((e0 >> 8) & (N_ - 1));
    int b = (int)(e0 >> 20);
    float cs = pcs[(size_t)b * N_ + m] + pcs[((size_t)B_ + b) * N_ + m];
    float inv = 1.f / (1e-9f + cs);
    short8v p0 = *(const short8v*)(pxr + e0);
    short8v p1 = *(const short8v*)(pxr + (size_t)B_ * N_ * 256 + e0);
    short8v xv = *(const short8v*)(dh + e0);
    short8v o;
#pragma unroll
    for (int j = 0; j < 8; ++j) {
        float xr = (bf2f((unsigned short)p0[j]) + bf2f((unsigned short)p1[j])) * inv;
        o[j] = (short)f2bf(bf2f((unsigned short)xv[j]) - xr);
    }
    *(short8v*)(dh + e0) = o;
}

// ------- t-conv + finalize (MFMA), 128-wide c-tile: out = xs + leaky(bn(t))
__global__ __launch_bounds__(512, 2) void convt_kernel(const unsigned short* __restrict__ dh,
                                                       const unsigned short* __restrict__ wh,
                                                       const float* __restrict__ bt,
                                                       const float* __restrict__ xs,
                                                       float* __restrict__ out,
                                                       const float* __restrict__ gam,
                                                       const float* __restrict__ bet,
                                                       const float* __restrict__ mu,
                                                       const float* __restrict__ var) {
    const int tid = threadIdx.x, wave = tid >> 6, lane = tid & 63, q = lane & 15, g = lane >> 4;
    const int m0 = blockIdx.x * 64, c0 = blockIdx.y * 128, b = blockIdx.z;
    const int cc = c0 + wave * 16;
    const unsigned short* db = dh + (size_t)b * N_ * 256;
    f32x4 acc[4];
#pragma unroll
    for (int j = 0; j < 4; ++j) acc[j] = (f32x4){0.f, 0.f, 0.f, 0.f};
    for (int ks = 0; ks < 8; ++ks) {
        short8v bw = *(const short8v*)(wh + (size_t)(cc + q) * 256 + ks * 32 + 8 * g);
#pragma unroll
        for (int j = 0; j < 4; ++j) {
            short8v ad = *(const short8v*)(db + (size_t)(m0 + j * 16 + q) * 256 + ks * 32 + 8 * g);
            acc[j] = __builtin_amdgcn_mfma_f32_16x16x32_bf16(ad, bw, acc[j], 0, 0, 0);
        }
    }
    const int c = cc + q;
    const float sc = rsqrtf(var[c] + 1e-5f) * gam[c];
    const float sh = bet[c] - mu[c] * sc;
    const float bb = bt[c];
#pragma unroll
    for (int j = 0; j < 4; ++j) {
        size_t off = ((size_t)b * C_ + c) * N_ + m0 + j * 16 + 4 * g;
        float4 xv = *(const float4*)(xs + off);
        float4 o;
        float tn;
        tn = (acc[j][0] + bb) * sc + sh; o.x = xv.x + (tn >= 0.f ? tn : 0.2f * tn);
        tn = (acc[j][1] + bb) * sc + sh; o.y = xv.y + (tn >= 0.f ? tn : 0.2f * tn);
        tn = (acc[j][2] + bb) * sc + sh; o.z = xv.z + (tn >= 0.f ? tn : 0.2f * tn);
        tn = (acc[j][3] + bb) * sc + sh; o.w = xv.w + (tn >= 0.f ? tn : 0.2f * tn);
        *(float4*)(out + off) = o;
    }
}

// ----------------------------------------------------------------------------------------
extern "C" void kernel_launch(void* const* d_in, const int* in_sizes, int n_in,
                              void* d_out, int out_size, void* d_ws, size_t ws_size,
                              hipStream_t stream) {
    (void)in_sizes; (void)n_in; (void)out_size; (void)ws_size;
    const float* x   = (const float*)d_in[0];
    const float* xyz = (const float*)d_in[1];
    const float* wqk = (const float*)d_in[2];
    const float* bqk = (const float*)d_in[3];
    const float* wv  = (const float*)d_in[4];
    const float* bv  = (const float*)d_in[5];
    const float* wt  = (const float*)d_in[6];
    const float* bt  = (const float*)d_in[7];
    const float* gam = (const float*)d_in[8];
    const float* bet = (const float*)d_in[9];
    const float* mu  = (const float*)d_in[10];
    const float* var = (const float*)d_in[11];
    float* out = (float*)d_out;

    const size_t M8 = (size_t)B_ * C_ * N_;   // 8M elements
    float* ws = (float*)d_ws;
    size_t off = 0;
    float* xs = ws + off;                              off += M8;       // fp32 [b][c][n] 32MB
    unsigned short* xst = (unsigned short*)(ws + off); off += M8 / 2;   // bf16 [b][n][c] 16MB
    unsigned short* Qf  = (unsigned short*)(ws + off); off += M8 / 8;   // bf16 frag-major 4MB
    unsigned short* Vf  = (unsigned short*)(ws + off); off += M8 / 2;   // bf16 frag-major 16MB
    unsigned short* wh  = (unsigned short*)(ws + off); off += 81920;    // bf16 weights
    float* pmax = ws + off; off += (size_t)JS_ * B_ * N_;
    float* psum = ws + off; off += (size_t)JS_ * B_ * N_;
    float* rmb  = ws + off; off += (size_t)B_ * N_;     // NEGATED row max
    float* rsb  = ws + off; off += (size_t)B_ * N_;
    float* pcs  = ws + off; off += (size_t)NSPLIT * B_ * N_;
    unsigned short* pxr = (unsigned short*)(ws + off); off += M8;       // bf16 [2][b][m][c] 32MB
    unsigned short* dhb = xst;   // reduce_diff updates xst in place -> dh

    wcvt_kernel<<<dim3(144), dim3(256), 0, stream>>>(wqk, wv, wt, wh);
    addt_kernel<<<dim3(N_ / 64, C_ / 64, B_), dim3(256), 0, stream>>>(x, xyz, xs, xst);
    convq_kernel<<<dim3(N_ / 64, B_), dim3(256), 0, stream>>>(xst, wh, bqk, Qf);
    rowstats_mfma<<<dim3(B_ * 32 * JS_), dim3(256), 0, stream>>>(Qf, pmax, psum);
    rowmerge_kernel<<<dim3(B_ * N_ / 256), dim3(256), 0, stream>>>(pmax, psum, rmb, rsb);
    convv_kernel<<<dim3(N_ / 64, C_ / 128, B_), dim3(512), 0, stream>>>(
        xst, wh + 16384, bv, rsb, Vf);
    pv_mfma32<<<dim3(B_ * 32 * NSPLIT), dim3(256), 0, stream>>>(Qf, Vf, rmb, rsb, pxr, pcs);
    reduce_diff<<<dim3(B_ * N_ * C_ / 8 / 256), dim3(256), 0, stream>>>(pxr, pcs, dhb);
    convt_kernel<<<dim3(N_ / 64, C_ / 128, B_), dim3(512), 0, stream>>>(
        dhb, wh + 81920, bt, xs, out, gam, bet, mu, var);
}

// Round 18
// 260.797 us; speedup vs baseline: 1.2086x; 1.0326x over previous
//
#include <hip/hip_runtime.h>
#include <math.h>

#define B_   8
#define C_   256
#define N_   4096
#define CQK_ 64
#define JS_  8
#define NSPLIT 2
#define NRANGE (N_ / NSPLIT)   // 2048

// Qf is pre-scaled by sqrt(log2(e)) so q.k logits are in log2 domain: exp -> v_exp_f32.
#define SCQ 1.20110674f
#define THR2 11.54f            // defer-max threshold (8 nats in log2 units)

typedef __attribute__((ext_vector_type(8))) short short8v;    // 8 x bf16 (4 VGPRs)
typedef __attribute__((ext_vector_type(4))) short short4v;    // 4 x bf16 (8B)
typedef __attribute__((ext_vector_type(4))) float f32x4;
typedef __attribute__((ext_vector_type(16))) float f32x16;
typedef __attribute__((ext_vector_type(4))) unsigned int uint4v;

__device__ __forceinline__ unsigned short f2bf(float f) {
    unsigned u = __float_as_uint(f);
    u += 0x7fffu + ((u >> 16) & 1u);
    return (unsigned short)(u >> 16);
}
__device__ __forceinline__ float bf2f(unsigned short h) {
    return __uint_as_float((unsigned)h << 16);
}
// Single-instruction exp2 via COMPILER BUILTIN (hazard-safe; r10's raw asm broke TRANS->VALU
// wait-state insertion). r14 A/B: halves pv VALU cycles (34->19% busy).
__device__ __forceinline__ float fexp2(float x) { return __builtin_amdgcn_exp2f(x); }
// NOTE: do NOT barrier-phase-lock waves for L1 reuse (r11). m=64/wave spills (r12).
// NOTE: do NOT pointer-bump/unroll-2 the pv loop (r13: load schedule destroyed).
// r15: occupancy register-capped at 2 waves/SIMD (VGPR+128 AGPR acc = 240/256 budget).
// r16: P shared via LDS (-2.5x V traffic) 158->130. r17: V-hoist above barrier 130->127.
// r18: n-tile 32->64 (one barrier per 64n, 32-MFMA PV cluster); V loads for granules 2,3
//      reuse granule-0,1 registers (sequential WAR) to stay under the 128-VGPR cliff.

// Fragment-major layouts (one wave load = contiguous 1KB):
//  Qf[b][nt(32n)][ks(16c)][lane][8]: element (n = nt*32 + (lane&31), c = ks*16 + (lane>>5)*8 + j)
//  Vf[b][nt16(16n)][cb(32c)][lane][8]: element (c = cb*32 + (lane&31), n = nt16*16 + (lane>>5)*8 + j)

// ------------------------------------------------ weights fp32 -> bf16 (row-major, packed)
__global__ __launch_bounds__(256) void wcvt_kernel(const float* __restrict__ wqk,
                                                   const float* __restrict__ wv,
                                                   const float* __restrict__ wt,
                                                   unsigned short* __restrict__ wh) {
    int i = (blockIdx.x * 256 + threadIdx.x) * 4;   // 144*256*4 = 147456 total
    const float* src; int off;
    if (i < 16384)      { src = wqk; off = i; }
    else if (i < 81920) { src = wv;  off = i - 16384; }
    else                { src = wt;  off = i - 81920; }
    float4 v = *(const float4*)(src + off);
    short4v o;
    o[0] = (short)f2bf(v.x); o[1] = (short)f2bf(v.y);
    o[2] = (short)f2bf(v.z); o[3] = (short)f2bf(v.w);
    *(short4v*)(wh + i) = o;
}

// --------------------------- xs = x + xyz (fp32 [b][c][n]) AND xst bf16 transposed [b][n][c]
__global__ __launch_bounds__(256) void addt_kernel(const float* __restrict__ x,
                                                   const float* __restrict__ xyz,
                                                   float* __restrict__ xs,
                                                   unsigned short* __restrict__ xst) {
    __shared__ float st[64][65];
    const int tid = threadIdx.x;
    const int n0 = blockIdx.x * 64, c0 = blockIdx.y * 64, b = blockIdx.z;
    const size_t base = ((size_t)b * C_ + c0) * N_ + n0;
#pragma unroll
    for (int r = 0; r < 4; ++r) {
        int c = r * 16 + (tid >> 4);
        int nc = (tid & 15) * 4;
        size_t off = base + (size_t)c * N_ + nc;
        float4 xv = *(const float4*)(x + off);
        float4 yv = *(const float4*)(xyz + off);
        float4 s = make_float4(xv.x + yv.x, xv.y + yv.y, xv.z + yv.z, xv.w + yv.w);
        *(float4*)(xs + off) = s;
        st[c][nc] = s.x; st[c][nc + 1] = s.y; st[c][nc + 2] = s.z; st[c][nc + 3] = s.w;
    }
    __syncthreads();
    int n = tid >> 2, cc = (tid & 3) * 16;
    short8v p0, p1;
#pragma unroll
    for (int j = 0; j < 8; ++j) {
        p0[j] = (short)f2bf(st[cc + j][n]);
        p1[j] = (short)f2bf(st[cc + 8 + j][n]);
    }
    size_t ob = ((size_t)b * N_ + n0 + n) * 256 + c0 + cc;
    *(short8v*)(xst + ob) = p0;
    *(short8v*)(xst + ob + 8) = p1;
}

// --------------------- Q-conv (MFMA): out Qf fragment-major, pre-scaled by SCQ (log2 domain)
__global__ __launch_bounds__(256, 4) void convq_kernel(const unsigned short* __restrict__ xst,
                                                       const unsigned short* __restrict__ wh,
                                                       const float* __restrict__ bias,
                                                       unsigned short* __restrict__ Qf) {
    const int tid = threadIdx.x, wave = tid >> 6, lane = tid & 63, q = lane & 15, g = lane >> 4;
    const int n0 = blockIdx.x * 64, b = blockIdx.y;
    const unsigned short* xb = xst + (size_t)b * N_ * 256;
    f32x4 acc[4];
#pragma unroll
    for (int j = 0; j < 4; ++j) acc[j] = (f32x4){0.f, 0.f, 0.f, 0.f};
    for (int ks = 0; ks < 8; ++ks) {
        short8v aw = *(const short8v*)(wh + (size_t)(wave * 16 + q) * 256 + ks * 32 + 8 * g);
#pragma unroll
        for (int j = 0; j < 4; ++j) {
            short8v bx = *(const short8v*)(xb + (size_t)(n0 + j * 16 + q) * 256 + ks * 32 + 8 * g);
            acc[j] = __builtin_amdgcn_mfma_f32_16x16x32_bf16(aw, bx, acc[j], 0, 0, 0);
        }
    }
    // element (n = n0+j*16+q, c = wave*16+4g+r) -> Qf[(b*128+nt)*4+ks=wave][hi=g>>1][l31][jj=4(g&1)+r]
#pragma unroll
    for (int j = 0; j < 4; ++j) {
        short4v pk;
#pragma unroll
        for (int r = 0; r < 4; ++r)
            pk[r] = (short)f2bf((acc[j][r] + bias[wave * 16 + 4 * g + r]) * SCQ);
        const int n = n0 + j * 16 + q;
        size_t a = ((((size_t)b * 128 + (n >> 5)) * 4 + wave) * 64 + (g >> 1) * 32 + (n & 31)) * 8
                   + (g & 1) * 4;
        *(short4v*)(Qf + a) = pk;
    }
}

// --------------------- V-conv (MFMA): out Vf fragment-major, PRE-SCALED by rsinv[n]
__global__ __launch_bounds__(512, 2) void convv_kernel(const unsigned short* __restrict__ xst,
                                                       const unsigned short* __restrict__ wh,
                                                       const float* __restrict__ bias,
                                                       const float* __restrict__ rsinv,
                                                       unsigned short* __restrict__ Vf) {
    const int tid = threadIdx.x, wave = tid >> 6, lane = tid & 63, q = lane & 15, g = lane >> 4;
    const int n0 = blockIdx.x * 64, o0 = blockIdx.y * 128, b = blockIdx.z;
    const int oo = o0 + wave * 16;
    const unsigned short* xb = xst + (size_t)b * N_ * 256;
    const float* rsb = rsinv + (size_t)b * N_;
    f32x4 acc[4];
#pragma unroll
    for (int j = 0; j < 4; ++j) acc[j] = (f32x4){0.f, 0.f, 0.f, 0.f};
    for (int ks = 0; ks < 8; ++ks) {
        short8v bw = *(const short8v*)(wh + (size_t)(oo + q) * 256 + ks * 32 + 8 * g);
#pragma unroll
        for (int j = 0; j < 4; ++j) {
            short8v ax = *(const short8v*)(xb + (size_t)(n0 + j * 16 + q) * 256 + ks * 32 + 8 * g);
            acc[j] = __builtin_amdgcn_mfma_f32_16x16x32_bf16(ax, bw, acc[j], 0, 0, 0);
        }
    }
    float bo = bias[oo + q];
    const int c = oo + q;
    // element (c, n = n0+j*16+4g+r) -> Vf[(b*256 + n0/16 + j)*8 + c>>5][hi=g>>1][c&31][4(g&1)+r]
#pragma unroll
    for (int j = 0; j < 4; ++j) {
        f32x4 rs4 = *(const f32x4*)(rsb + n0 + j * 16 + 4 * g);
        short4v pk;
#pragma unroll
        for (int r = 0; r < 4; ++r) pk[r] = (short)f2bf((acc[j][r] + bo) * rs4[r]);
        size_t a = ((((size_t)b * 256 + (n0 >> 4) + j) * 8 + (c >> 5)) * 64
                    + (g >> 1) * 32 + (c & 31)) * 8 + (g & 1) * 4;
        *(short4v*)(Vf + a) = pk;
    }
}

// ------------------ pass A: row softmax stats via 32x32 MFMA on Qf, log2 domain, defer-max
__global__ __launch_bounds__(256) void rowstats_mfma(const unsigned short* __restrict__ Qf,
                                                     float* __restrict__ pmax,
                                                     float* __restrict__ psum) {
    const int tid = threadIdx.x;
    const int wave = tid >> 6, lane = tid & 63, l31 = lane & 31;
    const int bid = blockIdx.x;
    const int b  = bid & 7;
    const int it = (bid >> 3) & 31;
    const int js = bid >> 8;
    const int i0 = it * 128 + wave * 32;
    const unsigned short* Qb = Qf + (size_t)b * 128 * 4 * 512;

    short8v bqi[4];   // B-frags: cols i (this wave's stat rows)
#pragma unroll
    for (int ks = 0; ks < 4; ++ks)
        bqi[ks] = *(const short8v*)(Qb + (((size_t)(i0 >> 5) * 4 + ks) * 64 + lane) * 8);

    float m = -1e30f, s = 0.f;
    const int jbeg = js * (N_ / JS_);
    for (int j0 = jbeg; j0 < jbeg + N_ / JS_; j0 += 32) {
        short8v an[4];
#pragma unroll
        for (int ks = 0; ks < 4; ++ks)
            an[ks] = *(const short8v*)(Qb + (((size_t)(j0 >> 5) * 4 + ks) * 64 + lane) * 8);
        f32x16 e;
#pragma unroll
        for (int r = 0; r < 16; ++r) e[r] = 0.f;
#pragma unroll
        for (int ks = 0; ks < 4; ++ks)
            e = __builtin_amdgcn_mfma_f32_32x32x16_bf16(an[ks], bqi[ks], e, 0, 0, 0);
        float pm = e[0];
#pragma unroll
        for (int r = 1; r < 16; ++r) pm = fmaxf(pm, e[r]);
        if (!__all(pm <= m + THR2)) {   // defer-max: rescale only on violation (rare)
            float mn = fmaxf(m, pm);
            s *= fexp2(m - mn);
            m = mn;
        }
#pragma unroll
        for (int r = 0; r < 16; ++r) s += fexp2(e[r] - m);
    }
    // merge hi/lo halves (each holds complementary j-subsets of column i = l31)
    {
        float mo = __shfl_xor(m, 32);
        float so = __shfl_xor(s, 32);
        float mn = fmaxf(m, mo);
        s = s * fexp2(m - mn) + so * fexp2(mo - mn);
        m = mn;
    }
    if (lane < 32) {
        size_t o = ((size_t)js * B_ + b) * N_ + i0 + l31;
        pmax[o] = m;
        psum[o] = s;
    }
}

// rowmerge: stores NEGATED rm (pv uses it directly as the MFMA C-init) + rsinv
__global__ __launch_bounds__(256) void rowmerge_kernel(const float* __restrict__ pmax,
                                                       const float* __restrict__ psum,
                                                       float* __restrict__ rmneg,
                                                       float* __restrict__ rsinv) {
    size_t i = (size_t)blockIdx.x * 256 + threadIdx.x;
    float m = -1e30f;
#pragma unroll
    for (int js = 0; js < JS_; ++js) m = fmaxf(m, pmax[(size_t)js * B_ * N_ + i]);
    float s = 0.f;
#pragma unroll
    for (int js = 0; js < JS_; ++js)
        s += psum[(size_t)js * B_ * N_ + i] * fexp2(pmax[(size_t)js * B_ * N_ + i] - m);
    rmneg[i] = -m;
    rsinv[i] = 1.f / s;
}

// --------- pass B: n-tile 64 = two energy passes (4 P granules of 16 rows) -> ONE barrier
// -> 32-MFMA PV cluster. P shared via double-buffered LDS; V granule-2/3 loads reuse the
// granule-0/1 registers (WAR) to stay under the 128-VGPR / 2-waves-per-SIMD cliff.
__global__ __launch_bounds__(256, 2) void pv_mfma32(const unsigned short* __restrict__ Qf,
                                                    const unsigned short* __restrict__ Vf,
                                                    const float* __restrict__ rmneg,
                                                    const float* __restrict__ rsinv,
                                                    unsigned short* __restrict__ pxr,
                                                    float* __restrict__ pcs) {
    __shared__ unsigned short Pl[2][4][4][64][8];   // [buf][mchunk][ngranule16][lane][8] = 32KB
    const int tid = threadIdx.x;
    const int wave = tid >> 6, lane = tid & 63, l31 = lane & 31, hi = lane >> 5;
    const int bid = blockIdx.x;
    const int b  = bid & 7;                 // XCD-pinned: one batch per XCD
    const int mc = (bid >> 3) & 31;
    const int ns = bid >> 8;
    const int m0 = mc * 128;                // block m-tile 128; wave's energy chunk = m0+wave*32
    const int nbeg = ns * NRANGE;
    const unsigned short* Qb = Qf + (size_t)b * 128 * 4 * 512;
    const unsigned short* Vb = Vf + (size_t)b * 256 * 8 * 512;
    const float* rmb = rmneg + (size_t)b * N_;
    const float* rsb = rsinv + (size_t)b * N_;

    // persistent energy B-frags for THIS wave's m-chunk: m = m0 + wave*32 + l31
    short8v bqm[4];
#pragma unroll
    for (int ks = 0; ks < 4; ++ks)
        bqm[ks] = *(const short8v*)(Qb + (((size_t)((m0 >> 5) + wave) * 4 + ks) * 64 + lane) * 8);

    f32x16 acc[4][2];   // [mchunk][cb]: m = m0+mk*32+l31, c = (wave*2+cb)*32 + 8s+4hi+r
#pragma unroll
    for (int mk = 0; mk < 4; ++mk)
#pragma unroll
        for (int cb = 0; cb < 2; ++cb)
#pragma unroll
            for (int r = 0; r < 16; ++r) acc[mk][cb][r] = 0.f;
    f32x4 csum4 = {0.f, 0.f, 0.f, 0.f};

#pragma unroll 1
    for (int it = 0; it < NRANGE / 64; ++it) {
        const int n0 = nbeg + it * 64;
        const int cur = it & 1;
        // ---- two energy passes (n-halves h=0,1), each publishing 2 P granules
#pragma unroll
        for (int h = 0; h < 2; ++h) {
            const int nh0 = n0 + h * 32;
            const int nt = nh0 >> 5;
            short8v an[4];
#pragma unroll
            for (int ks = 0; ks < 4; ++ks)
                an[ks] = *(const short8v*)(Qb + (((size_t)nt * 4 + ks) * 64 + lane) * 8);
            f32x4 rmn[4], rs[4];
#pragma unroll
            for (int s = 0; s < 4; ++s) {
                rmn[s] = *(const f32x4*)(rmb + nh0 + 8 * s + 4 * hi);
                rs[s]  = *(const f32x4*)(rsb + nh0 + 8 * s + 4 * hi);
            }
            f32x16 e;
#pragma unroll
            for (int s = 0; s < 4; ++s) {
                e[4 * s + 0] = rmn[s][0]; e[4 * s + 1] = rmn[s][1];
                e[4 * s + 2] = rmn[s][2]; e[4 * s + 3] = rmn[s][3];
            }
#pragma unroll
            for (int ks = 0; ks < 4; ++ks)
                e = __builtin_amdgcn_mfma_f32_32x32x16_bf16(an[ks], bqm[ks], e, 0, 0, 0);
            unsigned dw[8];
#pragma unroll
            for (int s = 0; s < 4; ++s) {
                float p0 = fexp2(e[4 * s + 0]);
                float p1 = fexp2(e[4 * s + 1]);
                float p2 = fexp2(e[4 * s + 2]);
                float p3 = fexp2(e[4 * s + 3]);
                csum4[s] += (p0 * rs[s][0] + p1 * rs[s][1]) + (p2 * rs[s][2] + p3 * rs[s][3]);
                asm("v_cvt_pk_bf16_f32 %0, %1, %2" : "=v"(dw[2 * s + 0]) : "v"(p0), "v"(p1));
                asm("v_cvt_pk_bf16_f32 %0, %1, %2" : "=v"(dw[2 * s + 1]) : "v"(p2), "v"(p3));
            }
            asm("v_permlane32_swap_b32 %0, %1" : "+v"(dw[0]), "+v"(dw[2]));
            asm("v_permlane32_swap_b32 %0, %1" : "+v"(dw[1]), "+v"(dw[3]));
            asm("v_permlane32_swap_b32 %0, %1" : "+v"(dw[4]), "+v"(dw[6]));
            asm("v_permlane32_swap_b32 %0, %1" : "+v"(dw[5]), "+v"(dw[7]));
            uint4v t0 = {dw[0], dw[1], dw[2], dw[3]};   // P rows nh0..nh0+15
            uint4v t1 = {dw[4], dw[5], dw[6], dw[7]};   // P rows nh0+16..nh0+31
            *(uint4v*)&Pl[cur][wave][2 * h + 0][lane][0] = t0;
            *(uint4v*)&Pl[cur][wave][2 * h + 1][lane][0] = t1;
        }
        // ---- V loads for granules 0,1 (issued before barrier; latency hides under sync)
        const size_t vq0 = (size_t)(n0 >> 4) * 8;   // Vf 16-n quarter index base
        short8v vreg[2][2];
#pragma unroll
        for (int gq = 0; gq < 2; ++gq) {
            vreg[gq][0] = *(const short8v*)(Vb + ((vq0 + gq * 8 + wave * 2 + 0) * 64 + lane) * 8);
            vreg[gq][1] = *(const short8v*)(Vb + ((vq0 + gq * 8 + wave * 2 + 1) * 64 + lane) * 8);
        }
        __syncthreads();
        // ---- PV: 32 MFMAs over 4 granules; granule-2/3 loads reuse vreg (WAR)
        __builtin_amdgcn_s_setprio(1);
#pragma unroll
        for (int gq = 0; gq < 2; ++gq) {
#pragma unroll
            for (int mk = 0; mk < 4; ++mk) {
                short8v pf = *(const short8v*)&Pl[cur][mk][gq][lane][0];
                acc[mk][0] = __builtin_amdgcn_mfma_f32_32x32x16_bf16(vreg[gq][0], pf,
                                                                     acc[mk][0], 0, 0, 0);
                acc[mk][1] = __builtin_amdgcn_mfma_f32_32x32x16_bf16(vreg[gq][1], pf,
                                                                     acc[mk][1], 0, 0, 0);
            }
        }
#pragma unroll
        for (int gq = 0; gq < 2; ++gq) {
            vreg[gq][0] = *(const short8v*)(Vb + ((vq0 + (2 + gq) * 8 + wave * 2 + 0) * 64 + lane) * 8);
            vreg[gq][1] = *(const short8v*)(Vb + ((vq0 + (2 + gq) * 8 + wave * 2 + 1) * 64 + lane) * 8);
        }
#pragma unroll
        for (int gq = 0; gq < 2; ++gq) {
#pragma unroll
            for (int mk = 0; mk < 4; ++mk) {
                short8v pf = *(const short8v*)&Pl[cur][mk][2 + gq][lane][0];
                acc[mk][0] = __builtin_amdgcn_mfma_f32_32x32x16_bf16(vreg[gq][0], pf,
                                                                     acc[mk][0], 0, 0, 0);
                acc[mk][1] = __builtin_amdgcn_mfma_f32_32x32x16_bf16(vreg[gq][1], pf,
                                                                     acc[mk][1], 0, 0, 0);
            }
        }
        __builtin_amdgcn_s_setprio(0);
    }

    // partial colsum for own m-chunk: lanes l and l+32 hold complementary n-halves
    float csum = (csum4[0] + csum4[1]) + (csum4[2] + csum4[3]);
    csum += __shfl_xor(csum, 32);
    if (lane < 32) pcs[((size_t)ns * B_ + b) * N_ + m0 + wave * 32 + l31] = csum;
    // partial XR out: bf16 [ns][b][m][c]; m = m0+mk*32+l31, c = (wave*2+cb)*32 + 8s + 4hi + r
    unsigned short* pb = pxr + ((size_t)ns * B_ + b) * N_ * 256;
#pragma unroll
    for (int mk = 0; mk < 4; ++mk) {
        const int m = m0 + mk * 32 + l31;
#pragma unroll
        for (int cb = 0; cb < 2; ++cb)
#pragma unroll
            for (int s = 0; s < 4; ++s) {
                short4v pk;
#pragma unroll
                for (int r = 0; r < 4; ++r) pk[r] = (short)f2bf(acc[mk][cb][4 * s + r]);
                *(short4v*)(pb + (size_t)m * 256 + (wave * 2 + cb) * 32 + 8 * s + 4 * hi) = pk;
            }
    }
}

// ------- reduce partials + diff, in place: dh[b][m][c] = bf16( xst - (p0+p1)/(1e-9+cs) )
__global__ __launch_bounds__(256) void reduce_diff(const unsigned short* __restrict__ pxr,
                                                   const float* __restrict__ pcs,
                                                   unsigned short* __restrict__ dh) {
    size_t i = (size_t)blockIdx.x * 256 + threadIdx.x;   // over B*N*C/8
    size_t e0 = i * 8;
    int m = (int)((e0 >> 8) & (N_ - 1));
    int b = (int)(e0 >> 20);
    float cs = pcs[(size_t)b * N_ + m] + pcs[((size_t)B_ + b) * N_ + m];
    float inv = 1.f / (1e-9f + cs);
    short8v p0 = *(const short8v*)(pxr + e0);
    short8v p1 = *(const short8v*)(pxr + (size_t)B_ * N_ * 256 + e0);
    short8v xv = *(const short8v*)(dh + e0);
    short8v o;
#pragma unroll
    for (int j = 0; j < 8; ++j) {
        float xr = (bf2f((unsigned short)p0[j]) + bf2f((unsigned short)p1[j])) * inv;
        o[j] = (short)f2bf(bf2f((unsigned short)xv[j]) - xr);
    }
    *(short8v*)(dh + e0) = o;
}

// ------- t-conv + finalize (MFMA), 128-wide c-tile: out = xs + leaky(bn(t))
__global__ __launch_bounds__(512, 2) void convt_kernel(const unsigned short* __restrict__ dh,
                                                       const unsigned short* __restrict__ wh,
                                                       const float* __restrict__ bt,
                                                       const float* __restrict__ xs,
                                                       float* __restrict__ out,
                                                       const float* __restrict__ gam,
                                                       const float* __restrict__ bet,
                                                       const float* __restrict__ mu,
                                                       const float* __restrict__ var) {
    const int tid = threadIdx.x, wave = tid >> 6, lane = tid & 63, q = lane & 15, g = lane >> 4;
    const int m0 = blockIdx.x * 64, c0 = blockIdx.y * 128, b = blockIdx.z;
    const int cc = c0 + wave * 16;
    const unsigned short* db = dh + (size_t)b * N_ * 256;
    f32x4 acc[4];
#pragma unroll
    for (int j = 0; j < 4; ++j) acc[j] = (f32x4){0.f, 0.f, 0.f, 0.f};
    for (int ks = 0; ks < 8; ++ks) {
        short8v bw = *(const short8v*)(wh + (size_t)(cc + q) * 256 + ks * 32 + 8 * g);
#pragma unroll
        for (int j = 0; j < 4; ++j) {
            short8v ad = *(const short8v*)(db + (size_t)(m0 + j * 16 + q) * 256 + ks * 32 + 8 * g);
            acc[j] = __builtin_amdgcn_mfma_f32_16x16x32_bf16(ad, bw, acc[j], 0, 0, 0);
        }
    }
    const int c = cc + q;
    const float sc = rsqrtf(var[c] + 1e-5f) * gam[c];
    const float sh = bet[c] - mu[c] * sc;
    const float bb = bt[c];
#pragma unroll
    for (int j = 0; j < 4; ++j) {
        size_t off = ((size_t)b * C_ + c) * N_ + m0 + j * 16 + 4 * g;
        float4 xv = *(const float4*)(xs + off);
        float4 o;
        float tn;
        tn = (acc[j][0] + bb) * sc + sh; o.x = xv.x + (tn >= 0.f ? tn : 0.2f * tn);
        tn = (acc[j][1] + bb) * sc + sh; o.y = xv.y + (tn >= 0.f ? tn : 0.2f * tn);
        tn = (acc[j][2] + bb) * sc + sh; o.z = xv.z + (tn >= 0.f ? tn : 0.2f * tn);
        tn = (acc[j][3] + bb) * sc + sh; o.w = xv.w + (tn >= 0.f ? tn : 0.2f * tn);
        *(float4*)(out + off) = o;
    }
}

// ----------------------------------------------------------------------------------------
extern "C" void kernel_launch(void* const* d_in, const int* in_sizes, int n_in,
                              void* d_out, int out_size, void* d_ws, size_t ws_size,
                              hipStream_t stream) {
    (void)in_sizes; (void)n_in; (void)out_size; (void)ws_size;
    const float* x   = (const float*)d_in[0];
    const float* xyz = (const float*)d_in[1];
    const float* wqk = (const float*)d_in[2];
    const float* bqk = (const float*)d_in[3];
    const float* wv  = (const float*)d_in[4];
    const float* bv  = (const float*)d_in[5];
    const float* wt  = (const float*)d_in[6];
    const float* bt  = (const float*)d_in[7];
    const float* gam = (const float*)d_in[8];
    const float* bet = (const float*)d_in[9];
    const float* mu  = (const float*)d_in[10];
    const float* var = (const float*)d_in[11];
    float* out = (float*)d_out;

    const size_t M8 = (size_t)B_ * C_ * N_;   // 8M elements
    float* ws = (float*)d_ws;
    size_t off = 0;
    float* xs = ws + off;                              off += M8;       // fp32 [b][c][n] 32MB
    unsigned short* xst = (unsigned short*)(ws + off); off += M8 / 2;   // bf16 [b][n][c] 16MB
    unsigned short* Qf  = (unsigned short*)(ws + off); off += M8 / 8;   // bf16 frag-major 4MB
    unsigned short* Vf  = (unsigned short*)(ws + off); off += M8 / 2;   // bf16 frag-major 16MB
    unsigned short* wh  = (unsigned short*)(ws + off); off += 81920;    // bf16 weights
    float* pmax = ws + off; off += (size_t)JS_ * B_ * N_;
    float* psum = ws + off; off += (size_t)JS_ * B_ * N_;
    float* rmb  = ws + off; off += (size_t)B_ * N_;     // NEGATED row max
    float* rsb  = ws + off; off += (size_t)B_ * N_;
    float* pcs  = ws + off; off += (size_t)NSPLIT * B_ * N_;
    unsigned short* pxr = (unsigned short*)(ws + off); off += M8;       // bf16 [2][b][m][c] 32MB
    unsigned short* dhb = xst;   // reduce_diff updates xst in place -> dh

    wcvt_kernel<<<dim3(144), dim3(256), 0, stream>>>(wqk, wv, wt, wh);
    addt_kernel<<<dim3(N_ / 64, C_ / 64, B_), dim3(256), 0, stream>>>(x, xyz, xs, xst);
    convq_kernel<<<dim3(N_ / 64, B_), dim3(256), 0, stream>>>(xst, wh, bqk, Qf);
    rowstats_mfma<<<dim3(B_ * 32 * JS_), dim3(256), 0, stream>>>(Qf, pmax, psum);
    rowmerge_kernel<<<dim3(B_ * N_ / 256), dim3(256), 0, stream>>>(pmax, psum, rmb, rsb);
    convv_kernel<<<dim3(N_ / 64, C_ / 128, B_), dim3(512), 0, stream>>>(
        xst, wh + 16384, bv, rsb, Vf);
    pv_mfma32<<<dim3(B_ * 32 * NSPLIT), dim3(256), 0, stream>>>(Qf, Vf, rmb, rsb, pxr, pcs);
    reduce_diff<<<dim3(B_ * N_ * C_ / 8 / 256), dim3(256), 0, stream>>>(pxr, pcs, dhb);
    convt_kernel<<<dim3(N_ / 64, C_ / 128, B_), dim3(512), 0, stream>>>(
        dhb, wh + 81920, bt, xs, out, gam, bet, mu, var);
}

// Round 20
// 260.534 us; speedup vs baseline: 1.2099x; 1.0010x over previous
//
#include <hip/hip_runtime.h>
#include <math.h>

#define B_   8
#define C_   256
#define N_   4096
#define CQK_ 64
#define JS_  8
#define NSPLIT 2
#define NRANGE (N_ / NSPLIT)   // 2048

// Qf is pre-scaled by sqrt(log2(e)) so q.k logits are in log2 domain: exp -> v_exp_f32.
#define SCQ 1.20110674f
#define THR2 11.54f            // defer-max threshold (8 nats in log2 units)

typedef __attribute__((ext_vector_type(8))) short short8v;    // 8 x bf16 (4 VGPRs)
typedef __attribute__((ext_vector_type(4))) short short4v;    // 4 x bf16 (8B)
typedef __attribute__((ext_vector_type(4))) float f32x4;
typedef __attribute__((ext_vector_type(16))) float f32x16;
typedef __attribute__((ext_vector_type(4))) unsigned int uint4v;

__device__ __forceinline__ unsigned short f2bf(float f) {
    unsigned u = __float_as_uint(f);
    u += 0x7fffu + ((u >> 16) & 1u);
    return (unsigned short)(u >> 16);
}
__device__ __forceinline__ float bf2f(unsigned short h) {
    return __uint_as_float((unsigned)h << 16);
}
// Single-instruction exp2 via COMPILER BUILTIN (hazard-safe; r10's raw asm broke TRANS->VALU
// wait-state insertion). r14 A/B: halves pv VALU cycles (34->19% busy).
__device__ __forceinline__ float fexp2(float x) { return __builtin_amdgcn_exp2f(x); }
// NOTE: do NOT barrier-phase-lock waves for L1 reuse (r11). m=64/wave spills (r12).
// NOTE: do NOT pointer-bump/unroll-2 the pv loop (r13: load schedule destroyed).
// r15: occupancy register-capped at 2 waves/SIMD (VGPR+128 AGPR acc = 240/256 budget).
// r16: P shared via LDS (-2.5x V traffic) 158->130. r17: V-hoist above barrier 130->127.
// r18: n-tile 64, 1 barrier/64n, 32-MFMA PV cluster: 127->115. VERIFIED BEST.
// r19: n-tile 128 (64KB LDS, 4-deep energy unroll) FAILED correctness — do not retry
//      without an independent race-screen; the r18 config is the accepted final state.

// Fragment-major layouts (one wave load = contiguous 1KB):
//  Qf[b][nt(32n)][ks(16c)][lane][8]: element (n = nt*32 + (lane&31), c = ks*16 + (lane>>5)*8 + j)
//  Vf[b][nt16(16n)][cb(32c)][lane][8]: element (c = cb*32 + (lane&31), n = nt16*16 + (lane>>5)*8 + j)

// ------------------------------------------------ weights fp32 -> bf16 (row-major, packed)
__global__ __launch_bounds__(256) void wcvt_kernel(const float* __restrict__ wqk,
                                                   const float* __restrict__ wv,
                                                   const float* __restrict__ wt,
                                                   unsigned short* __restrict__ wh) {
    int i = (blockIdx.x * 256 + threadIdx.x) * 4;   // 144*256*4 = 147456 total
    const float* src; int off;
    if (i < 16384)      { src = wqk; off = i; }
    else if (i < 81920) { src = wv;  off = i - 16384; }
    else                { src = wt;  off = i - 81920; }
    float4 v = *(const float4*)(src + off);
    short4v o;
    o[0] = (short)f2bf(v.x); o[1] = (short)f2bf(v.y);
    o[2] = (short)f2bf(v.z); o[3] = (short)f2bf(v.w);
    *(short4v*)(wh + i) = o;
}

// --------------------------- xs = x + xyz (fp32 [b][c][n]) AND xst bf16 transposed [b][n][c]
__global__ __launch_bounds__(256) void addt_kernel(const float* __restrict__ x,
                                                   const float* __restrict__ xyz,
                                                   float* __restrict__ xs,
                                                   unsigned short* __restrict__ xst) {
    __shared__ float st[64][65];
    const int tid = threadIdx.x;
    const int n0 = blockIdx.x * 64, c0 = blockIdx.y * 64, b = blockIdx.z;
    const size_t base = ((size_t)b * C_ + c0) * N_ + n0;
#pragma unroll
    for (int r = 0; r < 4; ++r) {
        int c = r * 16 + (tid >> 4);
        int nc = (tid & 15) * 4;
        size_t off = base + (size_t)c * N_ + nc;
        float4 xv = *(const float4*)(x + off);
        float4 yv = *(const float4*)(xyz + off);
        float4 s = make_float4(xv.x + yv.x, xv.y + yv.y, xv.z + yv.z, xv.w + yv.w);
        *(float4*)(xs + off) = s;
        st[c][nc] = s.x; st[c][nc + 1] = s.y; st[c][nc + 2] = s.z; st[c][nc + 3] = s.w;
    }
    __syncthreads();
    int n = tid >> 2, cc = (tid & 3) * 16;
    short8v p0, p1;
#pragma unroll
    for (int j = 0; j < 8; ++j) {
        p0[j] = (short)f2bf(st[cc + j][n]);
        p1[j] = (short)f2bf(st[cc + 8 + j][n]);
    }
    size_t ob = ((size_t)b * N_ + n0 + n) * 256 + c0 + cc;
    *(short8v*)(xst + ob) = p0;
    *(short8v*)(xst + ob + 8) = p1;
}

// --------------------- Q-conv (MFMA): out Qf fragment-major, pre-scaled by SCQ (log2 domain)
__global__ __launch_bounds__(256, 4) void convq_kernel(const unsigned short* __restrict__ xst,
                                                       const unsigned short* __restrict__ wh,
                                                       const float* __restrict__ bias,
                                                       unsigned short* __restrict__ Qf) {
    const int tid = threadIdx.x, wave = tid >> 6, lane = tid & 63, q = lane & 15, g = lane >> 4;
    const int n0 = blockIdx.x * 64, b = blockIdx.y;
    const unsigned short* xb = xst + (size_t)b * N_ * 256;
    f32x4 acc[4];
#pragma unroll
    for (int j = 0; j < 4; ++j) acc[j] = (f32x4){0.f, 0.f, 0.f, 0.f};
    for (int ks = 0; ks < 8; ++ks) {
        short8v aw = *(const short8v*)(wh + (size_t)(wave * 16 + q) * 256 + ks * 32 + 8 * g);
#pragma unroll
        for (int j = 0; j < 4; ++j) {
            short8v bx = *(const short8v*)(xb + (size_t)(n0 + j * 16 + q) * 256 + ks * 32 + 8 * g);
            acc[j] = __builtin_amdgcn_mfma_f32_16x16x32_bf16(aw, bx, acc[j], 0, 0, 0);
        }
    }
    // element (n = n0+j*16+q, c = wave*16+4g+r) -> Qf[(b*128+nt)*4+ks=wave][hi=g>>1][l31][jj=4(g&1)+r]
#pragma unroll
    for (int j = 0; j < 4; ++j) {
        short4v pk;
#pragma unroll
        for (int r = 0; r < 4; ++r)
            pk[r] = (short)f2bf((acc[j][r] + bias[wave * 16 + 4 * g + r]) * SCQ);
        const int n = n0 + j * 16 + q;
        size_t a = ((((size_t)b * 128 + (n >> 5)) * 4 + wave) * 64 + (g >> 1) * 32 + (n & 31)) * 8
                   + (g & 1) * 4;
        *(short4v*)(Qf + a) = pk;
    }
}

// --------------------- V-conv (MFMA): out Vf fragment-major, PRE-SCALED by rsinv[n]
__global__ __launch_bounds__(512, 2) void convv_kernel(const unsigned short* __restrict__ xst,
                                                       const unsigned short* __restrict__ wh,
                                                       const float* __restrict__ bias,
                                                       const float* __restrict__ rsinv,
                                                       unsigned short* __restrict__ Vf) {
    const int tid = threadIdx.x, wave = tid >> 6, lane = tid & 63, q = lane & 15, g = lane >> 4;
    const int n0 = blockIdx.x * 64, o0 = blockIdx.y * 128, b = blockIdx.z;
    const int oo = o0 + wave * 16;
    const unsigned short* xb = xst + (size_t)b * N_ * 256;
    const float* rsb = rsinv + (size_t)b * N_;
    f32x4 acc[4];
#pragma unroll
    for (int j = 0; j < 4; ++j) acc[j] = (f32x4){0.f, 0.f, 0.f, 0.f};
    for (int ks = 0; ks < 8; ++ks) {
        short8v bw = *(const short8v*)(wh + (size_t)(oo + q) * 256 + ks * 32 + 8 * g);
#pragma unroll
        for (int j = 0; j < 4; ++j) {
            short8v ax = *(const short8v*)(xb + (size_t)(n0 + j * 16 + q) * 256 + ks * 32 + 8 * g);
            acc[j] = __builtin_amdgcn_mfma_f32_16x16x32_bf16(ax, bw, acc[j], 0, 0, 0);
        }
    }
    float bo = bias[oo + q];
    const int c = oo + q;
    // element (c, n = n0+j*16+4g+r) -> Vf[(b*256 + n0/16 + j)*8 + c>>5][hi=g>>1][c&31][4(g&1)+r]
#pragma unroll
    for (int j = 0; j < 4; ++j) {
        f32x4 rs4 = *(const f32x4*)(rsb + n0 + j * 16 + 4 * g);
        short4v pk;
#pragma unroll
        for (int r = 0; r < 4; ++r) pk[r] = (short)f2bf((acc[j][r] + bo) * rs4[r]);
        size_t a = ((((size_t)b * 256 + (n0 >> 4) + j) * 8 + (c >> 5)) * 64
                    + (g >> 1) * 32 + (c & 31)) * 8 + (g & 1) * 4;
        *(short4v*)(Vf + a) = pk;
    }
}

// ------------------ pass A: row softmax stats via 32x32 MFMA on Qf, log2 domain, defer-max
__global__ __launch_bounds__(256) void rowstats_mfma(const unsigned short* __restrict__ Qf,
                                                     float* __restrict__ pmax,
                                                     float* __restrict__ psum) {
    const int tid = threadIdx.x;
    const int wave = tid >> 6, lane = tid & 63, l31 = lane & 31;
    const int bid = blockIdx.x;
    const int b  = bid & 7;
    const int it = (bid >> 3) & 31;
    const int js = bid >> 8;
    const int i0 = it * 128 + wave * 32;
    const unsigned short* Qb = Qf + (size_t)b * 128 * 4 * 512;

    short8v bqi[4];   // B-frags: cols i (this wave's stat rows)
#pragma unroll
    for (int ks = 0; ks < 4; ++ks)
        bqi[ks] = *(const short8v*)(Qb + (((size_t)(i0 >> 5) * 4 + ks) * 64 + lane) * 8);

    float m = -1e30f, s = 0.f;
    const int jbeg = js * (N_ / JS_);
    for (int j0 = jbeg; j0 < jbeg + N_ / JS_; j0 += 32) {
        short8v an[4];
#pragma unroll
        for (int ks = 0; ks < 4; ++ks)
            an[ks] = *(const short8v*)(Qb + (((size_t)(j0 >> 5) * 4 + ks) * 64 + lane) * 8);
        f32x16 e;
#pragma unroll
        for (int r = 0; r < 16; ++r) e[r] = 0.f;
#pragma unroll
        for (int ks = 0; ks < 4; ++ks)
            e = __builtin_amdgcn_mfma_f32_32x32x16_bf16(an[ks], bqi[ks], e, 0, 0, 0);
        float pm = e[0];
#pragma unroll
        for (int r = 1; r < 16; ++r) pm = fmaxf(pm, e[r]);
        if (!__all(pm <= m + THR2)) {   // defer-max: rescale only on violation (rare)
            float mn = fmaxf(m, pm);
            s *= fexp2(m - mn);
            m = mn;
        }
#pragma unroll
        for (int r = 0; r < 16; ++r) s += fexp2(e[r] - m);
    }
    // merge hi/lo halves (each holds complementary j-subsets of column i = l31)
    {
        float mo = __shfl_xor(m, 32);
        float so = __shfl_xor(s, 32);
        float mn = fmaxf(m, mo);
        s = s * fexp2(m - mn) + so * fexp2(mo - mn);
        m = mn;
    }
    if (lane < 32) {
        size_t o = ((size_t)js * B_ + b) * N_ + i0 + l31;
        pmax[o] = m;
        psum[o] = s;
    }
}

// rowmerge: stores NEGATED rm (pv uses it directly as the MFMA C-init) + rsinv
__global__ __launch_bounds__(256) void rowmerge_kernel(const float* __restrict__ pmax,
                                                       const float* __restrict__ psum,
                                                       float* __restrict__ rmneg,
                                                       float* __restrict__ rsinv) {
    size_t i = (size_t)blockIdx.x * 256 + threadIdx.x;
    float m = -1e30f;
#pragma unroll
    for (int js = 0; js < JS_; ++js) m = fmaxf(m, pmax[(size_t)js * B_ * N_ + i]);
    float s = 0.f;
#pragma unroll
    for (int js = 0; js < JS_; ++js)
        s += psum[(size_t)js * B_ * N_ + i] * fexp2(pmax[(size_t)js * B_ * N_ + i] - m);
    rmneg[i] = -m;
    rsinv[i] = 1.f / s;
}

// --------- pass B: n-tile 64 = two energy passes (4 P granules of 16 rows) -> ONE barrier
// -> 32-MFMA PV cluster. P shared via double-buffered LDS; V granule-2/3 loads reuse the
// granule-0/1 registers (WAR) to stay under the 128-VGPR / 2-waves-per-SIMD cliff.
__global__ __launch_bounds__(256, 2) void pv_mfma32(const unsigned short* __restrict__ Qf,
                                                    const unsigned short* __restrict__ Vf,
                                                    const float* __restrict__ rmneg,
                                                    const float* __restrict__ rsinv,
                                                    unsigned short* __restrict__ pxr,
                                                    float* __restrict__ pcs) {
    __shared__ unsigned short Pl[2][4][4][64][8];   // [buf][mchunk][ngranule16][lane][8] = 32KB
    const int tid = threadIdx.x;
    const int wave = tid >> 6, lane = tid & 63, l31 = lane & 31, hi = lane >> 5;
    const int bid = blockIdx.x;
    const int b  = bid & 7;                 // XCD-pinned: one batch per XCD
    const int mc = (bid >> 3) & 31;
    const int ns = bid >> 8;
    const int m0 = mc * 128;                // block m-tile 128; wave's energy chunk = m0+wave*32
    const int nbeg = ns * NRANGE;
    const unsigned short* Qb = Qf + (size_t)b * 128 * 4 * 512;
    const unsigned short* Vb = Vf + (size_t)b * 256 * 8 * 512;
    const float* rmb = rmneg + (size_t)b * N_;
    const float* rsb = rsinv + (size_t)b * N_;

    // persistent energy B-frags for THIS wave's m-chunk: m = m0 + wave*32 + l31
    short8v bqm[4];
#pragma unroll
    for (int ks = 0; ks < 4; ++ks)
        bqm[ks] = *(const short8v*)(Qb + (((size_t)((m0 >> 5) + wave) * 4 + ks) * 64 + lane) * 8);

    f32x16 acc[4][2];   // [mchunk][cb]: m = m0+mk*32+l31, c = (wave*2+cb)*32 + 8s+4hi+r
#pragma unroll
    for (int mk = 0; mk < 4; ++mk)
#pragma unroll
        for (int cb = 0; cb < 2; ++cb)
#pragma unroll
            for (int r = 0; r < 16; ++r) acc[mk][cb][r] = 0.f;
    f32x4 csum4 = {0.f, 0.f, 0.f, 0.f};

#pragma unroll 1
    for (int it = 0; it < NRANGE / 64; ++it) {
        const int n0 = nbeg + it * 64;
        const int cur = it & 1;
        // ---- two energy passes (n-halves h=0,1), each publishing 2 P granules
#pragma unroll
        for (int h = 0; h < 2; ++h) {
            const int nh0 = n0 + h * 32;
            const int nt = nh0 >> 5;
            short8v an[4];
#pragma unroll
            for (int ks = 0; ks < 4; ++ks)
                an[ks] = *(const short8v*)(Qb + (((size_t)nt * 4 + ks) * 64 + lane) * 8);
            f32x4 rmn[4], rs[4];
#pragma unroll
            for (int s = 0; s < 4; ++s) {
                rmn[s] = *(const f32x4*)(rmb + nh0 + 8 * s + 4 * hi);
                rs[s]  = *(const f32x4*)(rsb + nh0 + 8 * s + 4 * hi);
            }
            f32x16 e;
#pragma unroll
            for (int s = 0; s < 4; ++s) {
                e[4 * s + 0] = rmn[s][0]; e[4 * s + 1] = rmn[s][1];
                e[4 * s + 2] = rmn[s][2]; e[4 * s + 3] = rmn[s][3];
            }
#pragma unroll
            for (int ks = 0; ks < 4; ++ks)
                e = __builtin_amdgcn_mfma_f32_32x32x16_bf16(an[ks], bqm[ks], e, 0, 0, 0);
            unsigned dw[8];
#pragma unroll
            for (int s = 0; s < 4; ++s) {
                float p0 = fexp2(e[4 * s + 0]);
                float p1 = fexp2(e[4 * s + 1]);
                float p2 = fexp2(e[4 * s + 2]);
                float p3 = fexp2(e[4 * s + 3]);
                csum4[s] += (p0 * rs[s][0] + p1 * rs[s][1]) + (p2 * rs[s][2] + p3 * rs[s][3]);
                asm("v_cvt_pk_bf16_f32 %0, %1, %2" : "=v"(dw[2 * s + 0]) : "v"(p0), "v"(p1));
                asm("v_cvt_pk_bf16_f32 %0, %1, %2" : "=v"(dw[2 * s + 1]) : "v"(p2), "v"(p3));
            }
            asm("v_permlane32_swap_b32 %0, %1" : "+v"(dw[0]), "+v"(dw[2]));
            asm("v_permlane32_swap_b32 %0, %1" : "+v"(dw[1]), "+v"(dw[3]));
            asm("v_permlane32_swap_b32 %0, %1" : "+v"(dw[4]), "+v"(dw[6]));
            asm("v_permlane32_swap_b32 %0, %1" : "+v"(dw[5]), "+v"(dw[7]));
            uint4v t0 = {dw[0], dw[1], dw[2], dw[3]};   // P rows nh0..nh0+15
            uint4v t1 = {dw[4], dw[5], dw[6], dw[7]};   // P rows nh0+16..nh0+31
            *(uint4v*)&Pl[cur][wave][2 * h + 0][lane][0] = t0;
            *(uint4v*)&Pl[cur][wave][2 * h + 1][lane][0] = t1;
        }
        // ---- V loads for granules 0,1 (issued before barrier; latency hides under sync)
        const size_t vq0 = (size_t)(n0 >> 4) * 8;   // Vf 16-n quarter index base
        short8v vreg[2][2];
#pragma unroll
        for (int gq = 0; gq < 2; ++gq) {
            vreg[gq][0] = *(const short8v*)(Vb + ((vq0 + gq * 8 + wave * 2 + 0) * 64 + lane) * 8);
            vreg[gq][1] = *(const short8v*)(Vb + ((vq0 + gq * 8 + wave * 2 + 1) * 64 + lane) * 8);
        }
        __syncthreads();
        // ---- PV: 32 MFMAs over 4 granules; granule-2/3 loads reuse vreg (WAR)
        __builtin_amdgcn_s_setprio(1);
#pragma unroll
        for (int gq = 0; gq < 2; ++gq) {
#pragma unroll
            for (int mk = 0; mk < 4; ++mk) {
                short8v pf = *(const short8v*)&Pl[cur][mk][gq][lane][0];
                acc[mk][0] = __builtin_amdgcn_mfma_f32_32x32x16_bf16(vreg[gq][0], pf,
                                                                     acc[mk][0], 0, 0, 0);
                acc[mk][1] = __builtin_amdgcn_mfma_f32_32x32x16_bf16(vreg[gq][1], pf,
                                                                     acc[mk][1], 0, 0, 0);
            }
        }
#pragma unroll
        for (int gq = 0; gq < 2; ++gq) {
            vreg[gq][0] = *(const short8v*)(Vb + ((vq0 + (2 + gq) * 8 + wave * 2 + 0) * 64 + lane) * 8);
            vreg[gq][1] = *(const short8v*)(Vb + ((vq0 + (2 + gq) * 8 + wave * 2 + 1) * 64 + lane) * 8);
        }
#pragma unroll
        for (int gq = 0; gq < 2; ++gq) {
#pragma unroll
            for (int mk = 0; mk < 4; ++mk) {
                short8v pf = *(const short8v*)&Pl[cur][mk][2 + gq][lane][0];
                acc[mk][0] = __builtin_amdgcn_mfma_f32_32x32x16_bf16(vreg[gq][0], pf,
                                                                     acc[mk][0], 0, 0, 0);
                acc[mk][1] = __builtin_amdgcn_mfma_f32_32x32x16_bf16(vreg[gq][1], pf,
                                                                     acc[mk][1], 0, 0, 0);
            }
        }
        __builtin_amdgcn_s_setprio(0);
    }

    // partial colsum for own m-chunk: lanes l and l+32 hold complementary n-halves
    float csum = (csum4[0] + csum4[1]) + (csum4[2] + csum4[3]);
    csum += __shfl_xor(csum, 32);
    if (lane < 32) pcs[((size_t)ns * B_ + b) * N_ + m0 + wave * 32 + l31] = csum;
    // partial XR out: bf16 [ns][b][m][c]; m = m0+mk*32+l31, c = (wave*2+cb)*32 + 8s + 4hi + r
    unsigned short* pb = pxr + ((size_t)ns * B_ + b) * N_ * 256;
#pragma unroll
    for (int mk = 0; mk < 4; ++mk) {
        const int m = m0 + mk * 32 + l31;
#pragma unroll
        for (int cb = 0; cb < 2; ++cb)
#pragma unroll
            for (int s = 0; s < 4; ++s) {
                short4v pk;
#pragma unroll
                for (int r = 0; r < 4; ++r) pk[r] = (short)f2bf(acc[mk][cb][4 * s + r]);
                *(short4v*)(pb + (size_t)m * 256 + (wave * 2 + cb) * 32 + 8 * s + 4 * hi) = pk;
            }
    }
}

// ------- reduce partials + diff, in place: dh[b][m][c] = bf16( xst - (p0+p1)/(1e-9+cs) )
__global__ __launch_bounds__(256) void reduce_diff(const unsigned short* __restrict__ pxr,
                                                   const float* __restrict__ pcs,
                                                   unsigned short* __restrict__ dh) {
    size_t i = (size_t)blockIdx.x * 256 + threadIdx.x;   // over B*N*C/8
    size_t e0 = i * 8;
    int m = (int)((e0 >> 8) & (N_ - 1));
    int b = (int)(e0 >> 20);
    float cs = pcs[(size_t)b * N_ + m] + pcs[((size_t)B_ + b) * N_ + m];
    float inv = 1.f / (1e-9f + cs);
    short8v p0 = *(const short8v*)(pxr + e0);
    short8v p1 = *(const short8v*)(pxr + (size_t)B_ * N_ * 256 + e0);
    short8v xv = *(const short8v*)(dh + e0);
    short8v o;
#pragma unroll
    for (int j = 0; j < 8; ++j) {
        float xr = (bf2f((unsigned short)p0[j]) + bf2f((unsigned short)p1[j])) * inv;
        o[j] = (short)f2bf(bf2f((unsigned short)xv[j]) - xr);
    }
    *(short8v*)(dh + e0) = o;
}

// ------- t-conv + finalize (MFMA), 128-wide c-tile: out = xs + leaky(bn(t))
__global__ __launch_bounds__(512, 2) void convt_kernel(const unsigned short* __restrict__ dh,
                                                       const unsigned short* __restrict__ wh,
                                                       const float* __restrict__ bt,
                                                       const float* __restrict__ xs,
                                                       float* __restrict__ out,
                                                       const float* __restrict__ gam,
                                                       const float* __restrict__ bet,
                                                       const float* __restrict__ mu,
                                                       const float* __restrict__ var) {
    const int tid = threadIdx.x, wave = tid >> 6, lane = tid & 63, q = lane & 15, g = lane >> 4;
    const int m0 = blockIdx.x * 64, c0 = blockIdx.y * 128, b = blockIdx.z;
    const int cc = c0 + wave * 16;
    const unsigned short* db = dh + (size_t)b * N_ * 256;
    f32x4 acc[4];
#pragma unroll
    for (int j = 0; j < 4; ++j) acc[j] = (f32x4){0.f, 0.f, 0.f, 0.f};
    for (int ks = 0; ks < 8; ++ks) {
        short8v bw = *(const short8v*)(wh + (size_t)(cc + q) * 256 + ks * 32 + 8 * g);
#pragma unroll
        for (int j = 0; j < 4; ++j) {
            short8v ad = *(const short8v*)(db + (size_t)(m0 + j * 16 + q) * 256 + ks * 32 + 8 * g);
            acc[j] = __builtin_amdgcn_mfma_f32_16x16x32_bf16(ad, bw, acc[j], 0, 0, 0);
        }
    }
    const int c = cc + q;
    const float sc = rsqrtf(var[c] + 1e-5f) * gam[c];
    const float sh = bet[c] - mu[c] * sc;
    const float bb = bt[c];
#pragma unroll
    for (int j = 0; j < 4; ++j) {
        size_t off = ((size_t)b * C_ + c) * N_ + m0 + j * 16 + 4 * g;
        float4 xv = *(const float4*)(xs + off);
        float4 o;
        float tn;
        tn = (acc[j][0] + bb) * sc + sh; o.x = xv.x + (tn >= 0.f ? tn : 0.2f * tn);
        tn = (acc[j][1] + bb) * sc + sh; o.y = xv.y + (tn >= 0.f ? tn : 0.2f * tn);
        tn = (acc[j][2] + bb) * sc + sh; o.z = xv.z + (tn >= 0.f ? tn : 0.2f * tn);
        tn = (acc[j][3] + bb) * sc + sh; o.w = xv.w + (tn >= 0.f ? tn : 0.2f * tn);
        *(float4*)(out + off) = o;
    }
}

// ----------------------------------------------------------------------------------------
extern "C" void kernel_launch(void* const* d_in, const int* in_sizes, int n_in,
                              void* d_out, int out_size, void* d_ws, size_t ws_size,
                              hipStream_t stream) {
    (void)in_sizes; (void)n_in; (void)out_size; (void)ws_size;
    const float* x   = (const float*)d_in[0];
    const float* xyz = (const float*)d_in[1];
    const float* wqk = (const float*)d_in[2];
    const float* bqk = (const float*)d_in[3];
    const float* wv  = (const float*)d_in[4];
    const float* bv  = (const float*)d_in[5];
    const float* wt  = (const float*)d_in[6];
    const float* bt  = (const float*)d_in[7];
    const float* gam = (const float*)d_in[8];
    const float* bet = (const float*)d_in[9];
    const float* mu  = (const float*)d_in[10];
    const float* var = (const float*)d_in[11];
    float* out = (float*)d_out;

    const size_t M8 = (size_t)B_ * C_ * N_;   // 8M elements
    float* ws = (float*)d_ws;
    size_t off = 0;
    float* xs = ws + off;                              off += M8;       // fp32 [b][c][n] 32MB
    unsigned short* xst = (unsigned short*)(ws + off); off += M8 / 2;   // bf16 [b][n][c] 16MB
    unsigned short* Qf  = (unsigned short*)(ws + off); off += M8 / 8;   // bf16 frag-major 4MB
    unsigned short* Vf  = (unsigned short*)(ws + off); off += M8 / 2;   // bf16 frag-major 16MB
    unsigned short* wh  = (unsigned short*)(ws + off); off += 81920;    // bf16 weights
    float* pmax = ws + off; off += (size_t)JS_ * B_ * N_;
    float* psum = ws + off; off += (size_t)JS_ * B_ * N_;
    float* rmb  = ws + off; off += (size_t)B_ * N_;     // NEGATED row max
    float* rsb  = ws + off; off += (size_t)B_ * N_;
    float* pcs  = ws + off; off += (size_t)NSPLIT * B_ * N_;
    unsigned short* pxr = (unsigned short*)(ws + off); off += M8;       // bf16 [2][b][m][c] 32MB
    unsigned short* dhb = xst;   // reduce_diff updates xst in place -> dh

    wcvt_kernel<<<dim3(144), dim3(256), 0, stream>>>(wqk, wv, wt, wh);
    addt_kernel<<<dim3(N_ / 64, C_ / 64, B_), dim3(256), 0, stream>>>(x, xyz, xs, xst);
    convq_kernel<<<dim3(N_ / 64, B_), dim3(256), 0, stream>>>(xst, wh, bqk, Qf);
    rowstats_mfma<<<dim3(B_ * 32 * JS_), dim3(256), 0, stream>>>(Qf, pmax, psum);
    rowmerge_kernel<<<dim3(B_ * N_ / 256), dim3(256), 0, stream>>>(pmax, psum, rmb, rsb);
    convv_kernel<<<dim3(N_ / 64, C_ / 128, B_), dim3(512), 0, stream>>>(
        xst, wh + 16384, bv, rsb, Vf);
    pv_mfma32<<<dim3(B_ * 32 * NSPLIT), dim3(256), 0, stream>>>(Qf, Vf, rmb, rsb, pxr, pcs);
    reduce_diff<<<dim3(B_ * N_ * C_ / 8 / 256), dim3(256), 0, stream>>>(pxr, pcs, dhb);
    convt_kernel<<<dim3(N_ / 64, C_ / 128, B_), dim3(512), 0, stream>>>(
        dhb, wh + 81920, bt, xs, out, gam, bet, mu, var);
}